// Round 1
// baseline (1038.625 us; speedup 1.0000x reference)
//
#include <hip/hip_runtime.h>
#include <hip/hip_bf16.h>

#define BT 2
#define TT 2048
#define CC 1024
#define NH 16
#define HD 64

// ---------------------------------------------------------------------------
// GEMM: C[M,N] = A[M,K] * B[K,N] + bias[N]   (fp32, 64x64 tile, BK=32,
// 256 threads, 4x4 accumulator per thread, float4 LDS reads)
// ---------------------------------------------------------------------------
__global__ __launch_bounds__(256) void gemm_bias_f32(
    const float* __restrict__ A, const float* __restrict__ B,
    const float* __restrict__ bias, float* __restrict__ C,
    int M, int N, int K) {
  __shared__ __align__(16) float As[32 * 68];  // [k][m], row stride 68 floats
  __shared__ __align__(16) float Bs[32 * 68];  // [k][n], row stride 68 floats
  const int tid = threadIdx.x;
  const int tx = tid & 15;
  const int ty = tid >> 4;
  const int m0 = blockIdx.y * 64;
  const int n0 = blockIdx.x * 64;

  const int ac = (tid & 7) * 4;   // k-offset within A tile (0..28)
  const int ar = tid >> 3;        // row 0..31 (two passes -> 64 rows)
  const int bn = (tid & 15) * 4;  // n-offset within B tile
  const int bk = tid >> 4;        // k-row 0..15 (two passes -> 32 rows)

  float acc[4][4] = {};

  for (int k0 = 0; k0 < K; k0 += 32) {
#pragma unroll
    for (int p = 0; p < 2; ++p) {
      const int r = ar + p * 32;
      const float4 av = *reinterpret_cast<const float4*>(
          &A[(size_t)(m0 + r) * K + k0 + ac]);
      As[(ac + 0) * 68 + r] = av.x;
      As[(ac + 1) * 68 + r] = av.y;
      As[(ac + 2) * 68 + r] = av.z;
      As[(ac + 3) * 68 + r] = av.w;
      const int kk = bk + p * 16;
      const float4 bv = *reinterpret_cast<const float4*>(
          &B[(size_t)(k0 + kk) * N + n0 + bn]);
      *reinterpret_cast<float4*>(&Bs[kk * 68 + bn]) = bv;
    }
    __syncthreads();
#pragma unroll
    for (int k = 0; k < 32; ++k) {
      const float4 a4 = *reinterpret_cast<const float4*>(&As[k * 68 + ty * 4]);
      const float4 b4 = *reinterpret_cast<const float4*>(&Bs[k * 68 + tx * 4]);
      const float av[4] = {a4.x, a4.y, a4.z, a4.w};
      const float bv[4] = {b4.x, b4.y, b4.z, b4.w};
#pragma unroll
      for (int i = 0; i < 4; ++i)
#pragma unroll
        for (int j = 0; j < 4; ++j) acc[i][j] += av[i] * bv[j];
    }
    __syncthreads();
  }

#pragma unroll
  for (int i = 0; i < 4; ++i) {
    float4 ov;
    ov.x = acc[i][0] + bias[n0 + tx * 4 + 0];
    ov.y = acc[i][1] + bias[n0 + tx * 4 + 1];
    ov.z = acc[i][2] + bias[n0 + tx * 4 + 2];
    ov.w = acc[i][3] + bias[n0 + tx * 4 + 3];
    *reinterpret_cast<float4*>(
        &C[(size_t)(m0 + ty * 4 + i) * N + n0 + tx * 4]) = ov;
  }
}

// ---------------------------------------------------------------------------
// Flash-style causal attention (fp32).
// Grid: (T/64, B*NH). Block: 256 threads. Each block: 64 query rows of one
// (b,h), iterating 64-key tiles with online softmax.
// qkv layout: [B*T, 3C]; q at col h*64+c, k at 1024+h*64+c, v at 2048+h*64+c.
// y layout: [B*T, C] with head h occupying cols h*64..h*64+63.
// ---------------------------------------------------------------------------
__global__ __launch_bounds__(256) void attn_flash_f32(
    const float* __restrict__ qkv, const float* __restrict__ mask,
    float* __restrict__ y) {
  __shared__ __align__(16) float QsT[64 * 68];  // [c][r]  (transposed)
  __shared__ __align__(16) float KsT[64 * 68];  // [c][s]; reused as PsT [k][r]
  __shared__ __align__(16) float Vs[64 * 68];   // [s][c]
  __shared__ float red[64 * 17];
  __shared__ float m_run[64], l_run[64], alpha_s[64], mnew_s[64];
  float* PsT = KsT;  // P overwrites K tile (legal: K reads finish before sync C)

  const int tid = threadIdx.x;
  const int tx = tid & 15;
  const int ty = tid >> 4;
  const int bh = blockIdx.y;
  const int b = bh >> 4;
  const int h = bh & 15;
  const int t0 = blockIdx.x * 64;

  const int lc4 = (tid & 15) * 4;  // channel offset for staging loads
  const int lr = tid >> 4;         // row 0..15, 4 passes -> 64 rows

  // Load Q tile (transposed into LDS)
#pragma unroll
  for (int p = 0; p < 4; ++p) {
    const int r = lr + p * 16;
    const float4 qv = *reinterpret_cast<const float4*>(
        &qkv[(size_t)(b * TT + t0 + r) * (3 * CC) + h * HD + lc4]);
    QsT[(lc4 + 0) * 68 + r] = qv.x;
    QsT[(lc4 + 1) * 68 + r] = qv.y;
    QsT[(lc4 + 2) * 68 + r] = qv.z;
    QsT[(lc4 + 3) * 68 + r] = qv.w;
  }
  if (tid < 64) {
    m_run[tid] = -3.0e38f;
    l_run[tid] = 0.0f;
  }

  float o[4][4] = {};
  const float scale = 0.125f;  // 1/sqrt(64)
  const int ntiles = blockIdx.x + 1;

  for (int kt = 0; kt < ntiles; ++kt) {
    const int s0 = kt * 64;
    __syncthreads();  // A: prev-iteration PV reads of PsT/Vs are done
#pragma unroll
    for (int p = 0; p < 4; ++p) {
      const int r = lr + p * 16;
      const size_t base = (size_t)(b * TT + s0 + r) * (3 * CC) + h * HD + lc4;
      const float4 kv = *reinterpret_cast<const float4*>(&qkv[base + CC]);
      const float4 vv = *reinterpret_cast<const float4*>(&qkv[base + 2 * CC]);
      KsT[(lc4 + 0) * 68 + r] = kv.x;
      KsT[(lc4 + 1) * 68 + r] = kv.y;
      KsT[(lc4 + 2) * 68 + r] = kv.z;
      KsT[(lc4 + 3) * 68 + r] = kv.w;
      *reinterpret_cast<float4*>(&Vs[r * 68 + lc4]) = vv;
    }
    __syncthreads();  // B: K/V staged

    // S = Q K^T  (rows ty*4+i, key cols tx*4+j)
    float s[4][4] = {};
#pragma unroll 8
    for (int c = 0; c < 64; ++c) {
      const float4 a4 = *reinterpret_cast<const float4*>(&QsT[c * 68 + ty * 4]);
      const float4 b4 = *reinterpret_cast<const float4*>(&KsT[c * 68 + tx * 4]);
      const float av[4] = {a4.x, a4.y, a4.z, a4.w};
      const float bv[4] = {b4.x, b4.y, b4.z, b4.w};
#pragma unroll
      for (int i = 0; i < 4; ++i)
#pragma unroll
        for (int j = 0; j < 4; ++j) s[i][j] += av[i] * bv[j];
    }

    // scale, causal mask (-10000 like the reference), additive key mask
#pragma unroll
    for (int j = 0; j < 4; ++j) {
      const int sk = s0 + tx * 4 + j;
      const float mj = mask[b * TT + sk];
#pragma unroll
      for (int i = 0; i < 4; ++i) {
        const int tq = t0 + ty * 4 + i;
        float v = s[i][j] * scale;
        if (sk > tq) v = -10000.0f;
        s[i][j] = v + mj;
      }
    }

    // per-row partial max
#pragma unroll
    for (int i = 0; i < 4; ++i) {
      const float mx =
          fmaxf(fmaxf(s[i][0], s[i][1]), fmaxf(s[i][2], s[i][3]));
      red[(ty * 4 + i) * 17 + tx] = mx;
    }
    __syncthreads();  // C: partial maxes ready; all K-tile reads finished

    if (tid < 64) {
      float mx = red[tid * 17];
#pragma unroll
      for (int k2 = 1; k2 < 16; ++k2) mx = fmaxf(mx, red[tid * 17 + k2]);
      const float mo = m_run[tid];
      const float mn = fmaxf(mo, mx);
      mnew_s[tid] = mn;
      alpha_s[tid] = __expf(mo - mn);  // first tile: exp(-huge) -> 0
      m_run[tid] = mn;
    }
    __syncthreads();  // D: mnew/alpha visible

    // P = exp(S - m_new); write transposed into PsT; partial row sums;
    // rescale O accumulator
#pragma unroll
    for (int i = 0; i < 4; ++i) {
      const int r = ty * 4 + i;
      const float mn = mnew_s[r];
      const float al = alpha_s[r];
      float rs = 0.0f;
#pragma unroll
      for (int j = 0; j < 4; ++j) {
        const float p = __expf(s[i][j] - mn);
        PsT[(tx * 4 + j) * 68 + r] = p;
        rs += p;
        o[i][j] *= al;
      }
      red[r * 17 + tx] = rs;
    }
    __syncthreads();  // E: P + partial sums visible

    if (tid < 64) {
      float rs = 0.0f;
#pragma unroll
      for (int k2 = 0; k2 < 16; ++k2) rs += red[tid * 17 + k2];
      l_run[tid] = l_run[tid] * alpha_s[tid] + rs;
    }

    // O += P * V  (rows ty*4+i, dim cols tx*4+j)
#pragma unroll 8
    for (int k2 = 0; k2 < 64; ++k2) {
      const float4 p4 = *reinterpret_cast<const float4*>(&PsT[k2 * 68 + ty * 4]);
      const float4 v4 = *reinterpret_cast<const float4*>(&Vs[k2 * 68 + tx * 4]);
      const float pv[4] = {p4.x, p4.y, p4.z, p4.w};
      const float vv[4] = {v4.x, v4.y, v4.z, v4.w};
#pragma unroll
      for (int i = 0; i < 4; ++i)
#pragma unroll
        for (int j = 0; j < 4; ++j) o[i][j] += pv[i] * vv[j];
    }
  }

  __syncthreads();  // l_run final
#pragma unroll
  for (int i = 0; i < 4; ++i) {
    const int r = ty * 4 + i;
    const float li = 1.0f / l_run[r];
    float4 ov;
    ov.x = o[i][0] * li;
    ov.y = o[i][1] * li;
    ov.z = o[i][2] * li;
    ov.w = o[i][3] * li;
    *reinterpret_cast<float4*>(
        &y[(size_t)(b * TT + t0 + r) * CC + h * HD + tx * 4]) = ov;
  }
}

extern "C" void kernel_launch(void* const* d_in, const int* in_sizes, int n_in,
                              void* d_out, int out_size, void* d_ws,
                              size_t ws_size, hipStream_t stream) {
  const float* x = (const float*)d_in[0];        // [B,T,C]
  const float* attn_mask = (const float*)d_in[1];// [B,1,1,T]
  const float* W_attn = (const float*)d_in[2];   // [C,3C]
  const float* b_attn = (const float*)d_in[3];   // [3C]
  const float* W_proj = (const float*)d_in[4];   // [C,C]
  const float* b_proj = (const float*)d_in[5];   // [C]
  float* out = (float*)d_out;                    // [B,T,C]

  float* qkv = (float*)d_ws;                     // [B*T, 3C] = 48 MB
  float* y = qkv + (size_t)BT * TT * 3 * CC;     // [B*T, C]  = 16 MB

  const int M = BT * TT;  // 4096

  // 1) qkv = x @ W_attn + b_attn
  gemm_bias_f32<<<dim3((3 * CC) / 64, M / 64), 256, 0, stream>>>(
      x, W_attn, b_attn, qkv, M, 3 * CC, CC);

  // 2) flash attention -> y  (already in [B,T,C] layout)
  attn_flash_f32<<<dim3(TT / 64, BT * NH), 256, 0, stream>>>(qkv, attn_mask, y);

  // 3) out = y @ W_proj + b_proj
  gemm_bias_f32<<<dim3(CC / 64, M / 64), 256, 0, stream>>>(
      y, W_proj, b_proj, out, M, CC, CC);
}

// Round 3
// 302.098 us; speedup vs baseline: 3.4380x; 3.4380x over previous
//
#include <hip/hip_runtime.h>
#include <hip/hip_bf16.h>
#include <stdint.h>

#define BATCH 2
#define TT 2048
#define CC 1024
#define NH 16
#define HD 64

typedef __attribute__((ext_vector_type(8))) short short8;
typedef __attribute__((ext_vector_type(4))) float f32x4;

__device__ __forceinline__ short f2bf(float f) {
  union { float f; unsigned u; } x;
  x.f = f;
  unsigned r = x.u + 0x7FFFu + ((x.u >> 16) & 1u);
  return (short)(r >> 16);
}

// ---------------------------------------------------------------------------
// x [n] fp32 -> bf16 (as short), 8 elems/thread
// ---------------------------------------------------------------------------
__global__ __launch_bounds__(256) void cast_f32_bf16(
    const float* __restrict__ s, short* __restrict__ d, int n) {
  const int i = (blockIdx.x * 256 + threadIdx.x) * 8;
  if (i >= n) return;
  const float4 a = *reinterpret_cast<const float4*>(&s[i]);
  const float4 b = *reinterpret_cast<const float4*>(&s[i + 4]);
  short8 o;
  o[0] = f2bf(a.x); o[1] = f2bf(a.y); o[2] = f2bf(a.z); o[3] = f2bf(a.w);
  o[4] = f2bf(b.x); o[5] = f2bf(b.y); o[6] = f2bf(b.z); o[7] = f2bf(b.w);
  *reinterpret_cast<short8*>(&d[i]) = o;
}

// ---------------------------------------------------------------------------
// W [K,N] fp32 -> Wt [N,K] bf16, 64x64 tiles through LDS
// ---------------------------------------------------------------------------
__global__ __launch_bounds__(256) void transpose_cast_bf16(
    const float* __restrict__ W, short* __restrict__ Wt, int K, int N) {
  __shared__ __align__(16) float Ls[64][68];
  const int n0 = blockIdx.x * 64, k0 = blockIdx.y * 64;
  const int tid = threadIdx.x;
  {
    const int r = tid >> 4, c4 = (tid & 15) * 4;
#pragma unroll
    for (int p = 0; p < 4; ++p) {
      const float4 v = *reinterpret_cast<const float4*>(
          &W[(size_t)(k0 + r + p * 16) * N + n0 + c4]);
      *reinterpret_cast<float4*>(&Ls[r + p * 16][c4]) = v;
    }
  }
  __syncthreads();
  {
    const int n = tid >> 2;          // 0..63
    const int kk0 = (tid & 3) * 16;  // 0,16,32,48
#pragma unroll
    for (int half = 0; half < 2; ++half) {
      short8 o;
#pragma unroll
      for (int t = 0; t < 8; ++t) o[t] = f2bf(Ls[kk0 + half * 8 + t][n]);
      *reinterpret_cast<short8*>(&Wt[(size_t)(n0 + n) * K + k0 + kk0 + half * 8]) = o;
    }
  }
}

// ---------------------------------------------------------------------------
// GEMM (m97 structure): C[M,N] = A[M,K] * Bt[N,K]^T + bias
// A, Bt bf16 (as short), 128x128 tile, BK=32, 256 thr = 4 waves,
// each wave 64x64 via 4x4 grid of 16x16x32 MFMA. global_load_lds staging.
// ---------------------------------------------------------------------------
template <bool OUT_BF16>
__global__ __launch_bounds__(256) void gemm_bt_mfma(
    const short* __restrict__ A,   // [M,K] bf16
    const short* __restrict__ Bt,  // [N,K] bf16
    const float* __restrict__ bias,
    void* __restrict__ C, int M, int N, int K) {
  __shared__ __align__(16) short As[128 * 32];
  __shared__ __align__(16) short Bs[128 * 32];
  const int tid = threadIdx.x;
  const int w = tid >> 6, lane = tid & 63;
  const int quad = lane >> 4, l15 = lane & 15;
  const int m0 = blockIdx.y * 128, n0 = blockIdx.x * 128;
  const int wm = (w >> 1) * 64, wn = (w & 1) * 64;

  f32x4 acc[4][4] = {};

  const int srow = lane >> 2;       // 0..15
  const int scol = (lane & 3) * 8;  // 0,8,16,24

  for (int k0 = 0; k0 < K; k0 += 32) {
    __syncthreads();
#pragma unroll
    for (int p = 0; p < 2; ++p) {
      const int rb = __builtin_amdgcn_readfirstlane((w * 2 + p) * 16);
      const short* ga = &A[(size_t)(m0 + rb + srow) * K + k0 + scol];
      const short* gb = &Bt[(size_t)(n0 + rb + srow) * K + k0 + scol];
      __builtin_amdgcn_global_load_lds(
          (const __attribute__((address_space(1))) void*)ga,
          (__attribute__((address_space(3))) void*)&As[rb * 32], 16, 0, 0);
      __builtin_amdgcn_global_load_lds(
          (const __attribute__((address_space(1))) void*)gb,
          (__attribute__((address_space(3))) void*)&Bs[rb * 32], 16, 0, 0);
    }
    __syncthreads();

    short8 af[4], bfr[4];
#pragma unroll
    for (int i = 0; i < 4; ++i)
      af[i] = *reinterpret_cast<const short8*>(
          &As[(wm + i * 16 + l15) * 32 + quad * 8]);
#pragma unroll
    for (int j = 0; j < 4; ++j)
      bfr[j] = *reinterpret_cast<const short8*>(
          &Bs[(wn + j * 16 + l15) * 32 + quad * 8]);
#pragma unroll
    for (int i = 0; i < 4; ++i)
#pragma unroll
      for (int j = 0; j < 4; ++j)
        acc[i][j] = __builtin_amdgcn_mfma_f32_16x16x32_bf16(
            af[i], bfr[j], acc[i][j], 0, 0, 0);
  }

  // epilogue: row = m0+wm+i*16+quad*4+r, col = n0+wn+j*16+l15
#pragma unroll
  for (int i = 0; i < 4; ++i) {
#pragma unroll
    for (int r = 0; r < 4; ++r) {
      const int row = m0 + wm + i * 16 + quad * 4 + r;
#pragma unroll
      for (int j = 0; j < 4; ++j) {
        const int col = n0 + wn + j * 16 + l15;
        const float v = acc[i][j][r] + bias[col];
        if (OUT_BF16)
          ((short*)C)[(size_t)row * N + col] = f2bf(v);
        else
          ((float*)C)[(size_t)row * N + col] = v;
      }
    }
  }
}

// ---------------------------------------------------------------------------
// MFMA flash attention (bf16 inputs, fp32 softmax state/accum).
// Grid: (T/64, B*NH), block 256 = 4 waves. Each wave owns 16 query rows.
// qkv [B*T, 3C] bf16; y [B*T, C] bf16.
// ---------------------------------------------------------------------------
__global__ __launch_bounds__(256) void attn_mfma(
    const short* __restrict__ qkv, const float* __restrict__ mask,
    short* __restrict__ y) {
  __shared__ __align__(16) short Qs[64 * 72];
  __shared__ __align__(16) short Ks[64 * 72];
  __shared__ __align__(16) short Vt[64 * 72];  // [d][s]
  __shared__ __align__(16) short Ps[64 * 72];  // [q][s]
  const int tid = threadIdx.x;
  const int w = tid >> 6, lane = tid & 63;
  const int quad = lane >> 4, l15 = lane & 15;
  const int bh = blockIdx.y, b = bh >> 4, h = bh & 15;
  const int t0 = blockIdx.x * 64;
  const int RS = 3 * CC;  // qkv row stride (elems)

  // stage Q tile [64 rows][64 d]
  {
    const int r = tid >> 3, c8 = (tid & 7) * 8;
#pragma unroll
    for (int p = 0; p < 2; ++p) {
      const int rr = r + p * 32;
      const short8 v = *reinterpret_cast<const short8*>(
          &qkv[(size_t)(b * TT + t0 + rr) * RS + h * HD + c8]);
      *reinterpret_cast<short8*>(&Qs[rr * 72 + c8]) = v;
    }
  }

  float m_run[4], l_run[4];
  f32x4 o_acc[4] = {};
#pragma unroll
  for (int r = 0; r < 4; ++r) { m_run[r] = -1e30f; l_run[r] = 0.0f; }
  const float scale = 0.125f;  // 1/sqrt(64)

  for (int kt = 0; kt <= (int)blockIdx.x; ++kt) {
    const int s0 = kt * 64;
    __syncthreads();  // prior iteration's LDS reads complete
    // stage K tile [64 s][64 d]
    {
      const int r = tid >> 3, c8 = (tid & 7) * 8;
#pragma unroll
      for (int p = 0; p < 2; ++p) {
        const int rr = r + p * 32;
        const short8 v = *reinterpret_cast<const short8*>(
            &qkv[(size_t)(b * TT + s0 + rr) * RS + CC + h * HD + c8]);
        *reinterpret_cast<short8*>(&Ks[rr * 72 + c8]) = v;
      }
    }
    // stage V transposed: Vt[d][s]
    {
      const int s = tid >> 2, d0 = (tid & 3) * 16;
      const short* vp =
          &qkv[(size_t)(b * TT + s0 + s) * RS + 2 * CC + h * HD + d0];
      const short8 v0 = *reinterpret_cast<const short8*>(vp);
      const short8 v1 = *reinterpret_cast<const short8*>(vp + 8);
#pragma unroll
      for (int t = 0; t < 8; ++t) Vt[(d0 + t) * 72 + s] = v0[t];
#pragma unroll
      for (int t = 0; t < 8; ++t) Vt[(d0 + 8 + t) * 72 + s] = v1[t];
    }
    __syncthreads();  // K/Vt staged

    // S = Q K^T for this wave's 16 rows x 64 keys
    f32x4 s_acc[4] = {};
    short8 qf0 = *reinterpret_cast<const short8*>(
        &Qs[(w * 16 + l15) * 72 + quad * 8]);
    short8 qf1 = *reinterpret_cast<const short8*>(
        &Qs[(w * 16 + l15) * 72 + 32 + quad * 8]);
#pragma unroll
    for (int j = 0; j < 4; ++j) {
      short8 kf0 = *reinterpret_cast<const short8*>(
          &Ks[(j * 16 + l15) * 72 + quad * 8]);
      short8 kf1 = *reinterpret_cast<const short8*>(
          &Ks[(j * 16 + l15) * 72 + 32 + quad * 8]);
      s_acc[j] = __builtin_amdgcn_mfma_f32_16x16x32_bf16(qf0, kf0, s_acc[j], 0, 0, 0);
      s_acc[j] = __builtin_amdgcn_mfma_f32_16x16x32_bf16(qf1, kf1, s_acc[j], 0, 0, 0);
    }

    // scale + causal + additive mask; S[q=t0+w*16+quad*4+r][s=s0+j*16+l15]
    float mx[4] = {-1e30f, -1e30f, -1e30f, -1e30f};
#pragma unroll
    for (int j = 0; j < 4; ++j) {
      const int sg = s0 + j * 16 + l15;
      const float mj = mask[b * TT + sg];
#pragma unroll
      for (int r = 0; r < 4; ++r) {
        const int qg = t0 + w * 16 + quad * 4 + r;
        float v = s_acc[j][r] * scale;
        if (sg > qg) v = -10000.0f;
        v += mj;
        s_acc[j][r] = v;
        mx[r] = fmaxf(mx[r], v);
      }
    }
    // row max across the 16 lanes of this quad
#pragma unroll
    for (int d = 1; d < 16; d <<= 1)
#pragma unroll
      for (int r = 0; r < 4; ++r)
        mx[r] = fmaxf(mx[r], __shfl_xor(mx[r], d, 64));

    float alpha[4];
#pragma unroll
    for (int r = 0; r < 4; ++r) {
      const float mn = fmaxf(m_run[r], mx[r]);
      alpha[r] = __expf(m_run[r] - mn);
      m_run[r] = mn;
    }

    // P = exp(S - m), write bf16 to Ps[q][s]; partial row sums
    float rs[4] = {0.f, 0.f, 0.f, 0.f};
#pragma unroll
    for (int j = 0; j < 4; ++j) {
#pragma unroll
      for (int r = 0; r < 4; ++r) {
        const float p = __expf(s_acc[j][r] - m_run[r]);
        rs[r] += p;
        Ps[(w * 16 + quad * 4 + r) * 72 + j * 16 + l15] = f2bf(p);
      }
    }
#pragma unroll
    for (int d = 1; d < 16; d <<= 1)
#pragma unroll
      for (int r = 0; r < 4; ++r) rs[r] += __shfl_xor(rs[r], d, 64);
#pragma unroll
    for (int r = 0; r < 4; ++r) {
      l_run[r] = l_run[r] * alpha[r] + rs[r];
#pragma unroll
      for (int t = 0; t < 4; ++t) o_acc[t][r] *= alpha[r];
    }

    // O += P V  (wave reads only its own Ps rows; intra-wave DS ordering)
    short8 pf0 = *reinterpret_cast<const short8*>(
        &Ps[(w * 16 + l15) * 72 + quad * 8]);
    short8 pf1 = *reinterpret_cast<const short8*>(
        &Ps[(w * 16 + l15) * 72 + 32 + quad * 8]);
#pragma unroll
    for (int t = 0; t < 4; ++t) {
      short8 vf0 = *reinterpret_cast<const short8*>(
          &Vt[(t * 16 + l15) * 72 + quad * 8]);
      short8 vf1 = *reinterpret_cast<const short8*>(
          &Vt[(t * 16 + l15) * 72 + 32 + quad * 8]);
      o_acc[t] = __builtin_amdgcn_mfma_f32_16x16x32_bf16(pf0, vf0, o_acc[t], 0, 0, 0);
      o_acc[t] = __builtin_amdgcn_mfma_f32_16x16x32_bf16(pf1, vf1, o_acc[t], 0, 0, 0);
    }
  }

  // epilogue: y[q][h*64 + d] = O / l
#pragma unroll
  for (int t = 0; t < 4; ++t) {
#pragma unroll
    for (int r = 0; r < 4; ++r) {
      const float v = o_acc[t][r] / l_run[r];
      y[(size_t)(b * TT + t0 + w * 16 + quad * 4 + r) * CC + h * HD +
        t * 16 + l15] = f2bf(v);
    }
  }
}

extern "C" void kernel_launch(void* const* d_in, const int* in_sizes, int n_in,
                              void* d_out, int out_size, void* d_ws,
                              size_t ws_size, hipStream_t stream) {
  const float* x = (const float*)d_in[0];
  const float* attn_mask = (const float*)d_in[1];
  const float* W_attn = (const float*)d_in[2];
  const float* b_attn = (const float*)d_in[3];
  const float* W_proj = (const float*)d_in[4];
  const float* b_proj = (const float*)d_in[5];
  float* out = (float*)d_out;

  const int M = BATCH * TT;  // 4096

  short* xb = (short*)d_ws;                       // [4096,1024]
  short* wat = xb + (size_t)M * CC;               // [3072,1024]
  short* wpt = wat + (size_t)(3 * CC) * CC;       // [1024,1024]
  short* qkvb = wpt + (size_t)CC * CC;            // [4096,3072]
  short* yb = qkvb + (size_t)M * 3 * CC;          // [4096,1024]

  // prep: casts + weight transposes
  cast_f32_bf16<<<(M * CC) / (256 * 8), 256, 0, stream>>>(x, xb, M * CC);
  transpose_cast_bf16<<<dim3((3 * CC) / 64, CC / 64), 256, 0, stream>>>(
      W_attn, wat, CC, 3 * CC);
  transpose_cast_bf16<<<dim3(CC / 64, CC / 64), 256, 0, stream>>>(
      W_proj, wpt, CC, CC);

  // 1) qkv = x @ W_attn + b_attn  (bf16 out)
  gemm_bt_mfma<true><<<dim3((3 * CC) / 128, M / 128), 256, 0, stream>>>(
      xb, wat, b_attn, qkvb, M, 3 * CC, CC);

  // 2) flash attention -> y (bf16)
  attn_mfma<<<dim3(TT / 64, BATCH * NH), 256, 0, stream>>>(qkvb, attn_mask, yb);

  // 3) out = y @ W_proj + b_proj  (fp32 out)
  gemm_bt_mfma<false><<<dim3(CC / 128, M / 128), 256, 0, stream>>>(
      yb, wpt, b_proj, out, M, CC, CC);
}

// Round 4
// 261.155 us; speedup vs baseline: 3.9770x; 1.1568x over previous
//
#include <hip/hip_runtime.h>
#include <hip/hip_bf16.h>
#include <stdint.h>

#define BATCH 2
#define TT 2048
#define CC 1024
#define NH 16
#define HD 64

typedef __attribute__((ext_vector_type(8))) short short8;
typedef __attribute__((ext_vector_type(4))) short sh4;
typedef __attribute__((ext_vector_type(4))) float f32x4;

#define MFMA16 __builtin_amdgcn_mfma_f32_16x16x32_bf16

__device__ __forceinline__ short f2bf(float f) {
  union { float f; unsigned u; } x;
  x.f = f;
  unsigned r = x.u + 0x7FFFu + ((x.u >> 16) & 1u);
  return (short)(r >> 16);
}

// ---------------------------------------------------------------------------
// x [n] fp32 -> bf16 (as short), 8 elems/thread
// ---------------------------------------------------------------------------
__global__ __launch_bounds__(256) void cast_f32_bf16(
    const float* __restrict__ s, short* __restrict__ d, int n) {
  const int i = (blockIdx.x * 256 + threadIdx.x) * 8;
  if (i >= n) return;
  const float4 a = *reinterpret_cast<const float4*>(&s[i]);
  const float4 b = *reinterpret_cast<const float4*>(&s[i + 4]);
  short8 o;
  o[0] = f2bf(a.x); o[1] = f2bf(a.y); o[2] = f2bf(a.z); o[3] = f2bf(a.w);
  o[4] = f2bf(b.x); o[5] = f2bf(b.y); o[6] = f2bf(b.z); o[7] = f2bf(b.w);
  *reinterpret_cast<short8*>(&d[i]) = o;
}

// ---------------------------------------------------------------------------
// W [K,N] fp32 -> Wt [N,K] bf16, 64x64 tiles through LDS
// ---------------------------------------------------------------------------
__global__ __launch_bounds__(256) void transpose_cast_bf16(
    const float* __restrict__ W, short* __restrict__ Wt, int K, int N) {
  __shared__ __align__(16) float Ls[64][68];
  const int n0 = blockIdx.x * 64, k0 = blockIdx.y * 64;
  const int tid = threadIdx.x;
  {
    const int r = tid >> 4, c4 = (tid & 15) * 4;
#pragma unroll
    for (int p = 0; p < 4; ++p) {
      const float4 v = *reinterpret_cast<const float4*>(
          &W[(size_t)(k0 + r + p * 16) * N + n0 + c4]);
      *reinterpret_cast<float4*>(&Ls[r + p * 16][c4]) = v;
    }
  }
  __syncthreads();
  {
    const int n = tid >> 2;
    const int kk0 = (tid & 3) * 16;
#pragma unroll
    for (int half = 0; half < 2; ++half) {
      short8 o;
#pragma unroll
      for (int t = 0; t < 8; ++t) o[t] = f2bf(Ls[kk0 + half * 8 + t][n]);
      *reinterpret_cast<short8*>(&Wt[(size_t)(n0 + n) * K + k0 + kk0 + half * 8]) = o;
    }
  }
}

// ---------------------------------------------------------------------------
// v slice of qkv -> vT[b][h][d][s]  (bf16), 64x64 tiles through LDS
// ---------------------------------------------------------------------------
__global__ __launch_bounds__(256) void transpose_v(
    const short* __restrict__ qkv, short* __restrict__ vT) {
  __shared__ __align__(16) short Ls[64][72];
  const int s0 = blockIdx.x * 64;
  const int bh = blockIdx.y, b = bh >> 4, h = bh & 15;
  const int tid = threadIdx.x;
  const int r = tid >> 3, c = (tid & 7) * 8;
#pragma unroll
  for (int p = 0; p < 2; ++p) {
    *reinterpret_cast<short8*>(&Ls[r + p * 32][c]) =
        *reinterpret_cast<const short8*>(
            &qkv[(size_t)(b * TT + s0 + r + p * 32) * (3 * CC) + 2 * CC +
                 h * HD + c]);
  }
  __syncthreads();
  const int d = tid >> 2, ss = (tid & 3) * 16;
  short8 o0, o1;
#pragma unroll
  for (int t = 0; t < 8; ++t) { o0[t] = Ls[ss + t][d]; o1[t] = Ls[ss + 8 + t][d]; }
  short* dst = &vT[((size_t)(bh * HD + d)) * TT + s0 + ss];
  *reinterpret_cast<short8*>(dst) = o0;
  *reinterpret_cast<short8*>(dst + 8) = o1;
}

// ---------------------------------------------------------------------------
// GEMM (m97 structure): C[M,N] = A[M,K] * Bt[N,K]^T + bias
// ---------------------------------------------------------------------------
template <bool OUT_BF16>
__global__ __launch_bounds__(256) void gemm_bt_mfma(
    const short* __restrict__ A, const short* __restrict__ Bt,
    const float* __restrict__ bias, void* __restrict__ C, int M, int N, int K) {
  __shared__ __align__(16) short As[128 * 32];
  __shared__ __align__(16) short Bs[128 * 32];
  const int tid = threadIdx.x;
  const int w = tid >> 6, lane = tid & 63;
  const int quad = lane >> 4, l15 = lane & 15;
  const int m0 = blockIdx.y * 128, n0 = blockIdx.x * 128;
  const int wm = (w >> 1) * 64, wn = (w & 1) * 64;

  f32x4 acc[4][4] = {};
  const int srow = lane >> 2;
  const int scol = (lane & 3) * 8;

  for (int k0 = 0; k0 < K; k0 += 32) {
    __syncthreads();
#pragma unroll
    for (int p = 0; p < 2; ++p) {
      const int rb = __builtin_amdgcn_readfirstlane((w * 2 + p) * 16);
      const short* ga = &A[(size_t)(m0 + rb + srow) * K + k0 + scol];
      const short* gb = &Bt[(size_t)(n0 + rb + srow) * K + k0 + scol];
      __builtin_amdgcn_global_load_lds(
          (const __attribute__((address_space(1))) void*)ga,
          (__attribute__((address_space(3))) void*)&As[rb * 32], 16, 0, 0);
      __builtin_amdgcn_global_load_lds(
          (const __attribute__((address_space(1))) void*)gb,
          (__attribute__((address_space(3))) void*)&Bs[rb * 32], 16, 0, 0);
    }
    __syncthreads();

    short8 af[4], bfr[4];
#pragma unroll
    for (int i = 0; i < 4; ++i)
      af[i] = *reinterpret_cast<const short8*>(
          &As[(wm + i * 16 + l15) * 32 + quad * 8]);
#pragma unroll
    for (int j = 0; j < 4; ++j)
      bfr[j] = *reinterpret_cast<const short8*>(
          &Bs[(wn + j * 16 + l15) * 32 + quad * 8]);
#pragma unroll
    for (int i = 0; i < 4; ++i)
#pragma unroll
      for (int j = 0; j < 4; ++j)
        acc[i][j] = MFMA16(af[i], bfr[j], acc[i][j], 0, 0, 0);
  }

#pragma unroll
  for (int i = 0; i < 4; ++i) {
#pragma unroll
    for (int r = 0; r < 4; ++r) {
      const int row = m0 + wm + i * 16 + quad * 4 + r;
#pragma unroll
      for (int j = 0; j < 4; ++j) {
        const int col = n0 + wn + j * 16 + l15;
        const float v = acc[i][j][r] + bias[col];
        if (OUT_BF16)
          ((short*)C)[(size_t)row * N + col] = f2bf(v);
        else
          ((float*)C)[(size_t)row * N + col] = v;
      }
    }
  }
}

// ---------------------------------------------------------------------------
// MFMA flash attention v2: S^T = K Q^T trick, vectorized P/V LDS paths.
// Grid: (T/128, B*NH), block 256 = 4 waves; each wave 32 q rows (2 strips).
// ---------------------------------------------------------------------------
#define PST 72
__global__ __launch_bounds__(256) void attn_mfma2(
    const short* __restrict__ qkv, const short* __restrict__ vT,
    const float* __restrict__ mask, short* __restrict__ y) {
  __shared__ __align__(16) short Ks[64 * PST];
  __shared__ __align__(16) short Vs[64 * PST];   // V^T tile [d][s]
  __shared__ __align__(16) short Ps[128 * PST];  // P [q_local][s]
  const int tid = threadIdx.x;
  const int w = tid >> 6, lane = tid & 63;
  const int quad = lane >> 4, l15 = lane & 15;
  const int bh = blockIdx.y, b = bh >> 4, h = bh & 15;
  const int qi = gridDim.x - 1 - blockIdx.x;  // heavy blocks first
  const int q0 = qi * 128;
  const int RS = 3 * CC;

  // Q fragments in registers (B-operand): per strip, per k-half
  short8 qf[2][2];
#pragma unroll
  for (int st = 0; st < 2; ++st) {
    const size_t qrow = (size_t)(b * TT + q0 + w * 32 + st * 16 + l15) * RS +
                        h * HD + quad * 8;
    qf[st][0] = *reinterpret_cast<const short8*>(&qkv[qrow]);
    qf[st][1] = *reinterpret_cast<const short8*>(&qkv[qrow + 32]);
  }

  float m_run[2] = {-1e30f, -1e30f}, l_run[2] = {0.f, 0.f};
  f32x4 o_acc[2][4] = {};

  const int nt = 2 * qi + 2;
  const int sr = tid >> 3, sc = (tid & 7) * 8;

  for (int kt = 0; kt < nt; ++kt) {
    const int s0 = kt * 64;
    __syncthreads();
#pragma unroll
    for (int p = 0; p < 2; ++p) {
      const int rr = sr + p * 32;
      *reinterpret_cast<short8*>(&Ks[rr * PST + sc]) =
          *reinterpret_cast<const short8*>(
              &qkv[(size_t)(b * TT + s0 + rr) * RS + CC + h * HD + sc]);
      *reinterpret_cast<short8*>(&Vs[rr * PST + sc]) =
          *reinterpret_cast<const short8*>(
              &vT[((size_t)(bh * HD + rr)) * TT + s0 + sc]);
    }
    __syncthreads();

    // additive mask (consecutive s per lane-reg)
    f32x4 mv[4];
#pragma unroll
    for (int j = 0; j < 4; ++j)
      mv[j] = *reinterpret_cast<const f32x4*>(
          &mask[b * TT + s0 + j * 16 + quad * 4]);

    // S^T = K Q^T for both strips (K frags transient)
    f32x4 sa[2][4] = {};
    const bool act0 = (s0 <= q0 + w * 32 + 15);
    const bool act1 = (s0 <= q0 + w * 32 + 31);
#pragma unroll
    for (int j = 0; j < 4; ++j) {
      const short8 kf0 = *reinterpret_cast<const short8*>(
          &Ks[(j * 16 + l15) * PST + quad * 8]);
      const short8 kf1 = *reinterpret_cast<const short8*>(
          &Ks[(j * 16 + l15) * PST + 32 + quad * 8]);
      if (act0) {
        sa[0][j] = MFMA16(kf0, qf[0][0], sa[0][j], 0, 0, 0);
        sa[0][j] = MFMA16(kf1, qf[0][1], sa[0][j], 0, 0, 0);
      }
      if (act1) {
        sa[1][j] = MFMA16(kf0, qf[1][0], sa[1][j], 0, 0, 0);
        sa[1][j] = MFMA16(kf1, qf[1][1], sa[1][j], 0, 0, 0);
      }
    }

#pragma unroll
    for (int st = 0; st < 2; ++st) {
      if (st == 0 ? !act0 : !act1) continue;
      const int qg = q0 + w * 32 + st * 16 + l15;  // this lane's q row
      float mx = -1e30f;
#pragma unroll
      for (int j = 0; j < 4; ++j) {
#pragma unroll
        for (int r = 0; r < 4; ++r) {
          const int sg = s0 + j * 16 + quad * 4 + r;
          float v = (sg > qg) ? -10000.0f : sa[st][j][r] * 0.125f;
          v += mv[j][r];
          sa[st][j][r] = v;
          mx = fmaxf(mx, v);
        }
      }
      mx = fmaxf(mx, __shfl_xor(mx, 16, 64));
      mx = fmaxf(mx, __shfl_xor(mx, 32, 64));
      const float mn = fmaxf(m_run[st], mx);
      const float alpha = __expf(m_run[st] - mn);
      m_run[st] = mn;

      float rs = 0.f;
#pragma unroll
      for (int j = 0; j < 4; ++j) {
        sh4 pw;
#pragma unroll
        for (int r = 0; r < 4; ++r) {
          const float p = __expf(sa[st][j][r] - mn);
          rs += p;
          pw[r] = f2bf(p);
        }
        *reinterpret_cast<sh4*>(
            &Ps[(w * 32 + st * 16 + l15) * PST + j * 16 + quad * 4]) = pw;
      }
      rs += __shfl_xor(rs, 16, 64);
      rs += __shfl_xor(rs, 32, 64);
      l_run[st] = l_run[st] * alpha + rs;

      // rescale O rows (alpha for row quad*4+r lives at lane quad*4+r)
#pragma unroll
      for (int r = 0; r < 4; ++r) {
        const float ar = __shfl(alpha, quad * 4 + r, 64);
#pragma unroll
        for (int t = 0; t < 4; ++t) o_acc[st][t][r] *= ar;
      }

      // O += P V   (P rows owned by this wave; intra-wave LDS ordering)
      const short8 pf0 = *reinterpret_cast<const short8*>(
          &Ps[(w * 32 + st * 16 + l15) * PST + quad * 8]);
      const short8 pf1 = *reinterpret_cast<const short8*>(
          &Ps[(w * 32 + st * 16 + l15) * PST + 32 + quad * 8]);
#pragma unroll
      for (int t = 0; t < 4; ++t) {
        const short8 vf0 = *reinterpret_cast<const short8*>(
            &Vs[(t * 16 + l15) * PST + quad * 8]);
        const short8 vf1 = *reinterpret_cast<const short8*>(
            &Vs[(t * 16 + l15) * PST + 32 + quad * 8]);
        o_acc[st][t] = MFMA16(pf0, vf0, o_acc[st][t], 0, 0, 0);
        o_acc[st][t] = MFMA16(pf1, vf1, o_acc[st][t], 0, 0, 0);
      }
    }
  }

  // epilogue
#pragma unroll
  for (int st = 0; st < 2; ++st) {
#pragma unroll
    for (int r = 0; r < 4; ++r) {
      const float lr = __shfl(l_run[st], quad * 4 + r, 64);
      const float inv = 1.0f / lr;
      const size_t row = (size_t)(b * TT + q0 + w * 32 + st * 16 + quad * 4 + r);
#pragma unroll
      for (int t = 0; t < 4; ++t)
        y[row * CC + h * HD + t * 16 + l15] = f2bf(o_acc[st][t][r] * inv);
    }
  }
}

extern "C" void kernel_launch(void* const* d_in, const int* in_sizes, int n_in,
                              void* d_out, int out_size, void* d_ws,
                              size_t ws_size, hipStream_t stream) {
  const float* x = (const float*)d_in[0];
  const float* attn_mask = (const float*)d_in[1];
  const float* W_attn = (const float*)d_in[2];
  const float* b_attn = (const float*)d_in[3];
  const float* W_proj = (const float*)d_in[4];
  const float* b_proj = (const float*)d_in[5];
  float* out = (float*)d_out;

  const int M = BATCH * TT;  // 4096

  short* xb = (short*)d_ws;                       // [4096,1024]
  short* wat = xb + (size_t)M * CC;               // [3072,1024]
  short* wpt = wat + (size_t)(3 * CC) * CC;       // [1024,1024]
  short* qkvb = wpt + (size_t)CC * CC;            // [4096,3072]
  short* yb = qkvb + (size_t)M * 3 * CC;          // [4096,1024]
  short* vTb = yb + (size_t)M * CC;               // [2*16*64, 2048]

  cast_f32_bf16<<<(M * CC) / (256 * 8), 256, 0, stream>>>(x, xb, M * CC);
  transpose_cast_bf16<<<dim3((3 * CC) / 64, CC / 64), 256, 0, stream>>>(
      W_attn, wat, CC, 3 * CC);
  transpose_cast_bf16<<<dim3(CC / 64, CC / 64), 256, 0, stream>>>(
      W_proj, wpt, CC, CC);

  gemm_bt_mfma<true><<<dim3((3 * CC) / 128, M / 128), 256, 0, stream>>>(
      xb, wat, b_attn, qkvb, M, 3 * CC, CC);

  transpose_v<<<dim3(TT / 64, BATCH * NH), 256, 0, stream>>>(qkvb, vTb);

  attn_mfma2<<<dim3(TT / 128, BATCH * NH), 256, 0, stream>>>(
      qkvb, vTb, attn_mask, yb);

  gemm_bt_mfma<false><<<dim3(CC / 128, M / 128), 256, 0, stream>>>(
      yb, wpt, b_proj, out, M, CC, CC);
}

// Round 5
// 239.933 us; speedup vs baseline: 4.3288x; 1.0884x over previous
//
#include <hip/hip_runtime.h>
#include <hip/hip_bf16.h>
#include <stdint.h>

#define BATCH 2
#define TT 2048
#define CC 1024
#define NH 16
#define HD 64

typedef __attribute__((ext_vector_type(8))) short short8;
typedef __attribute__((ext_vector_type(4))) short sh4;
typedef __attribute__((ext_vector_type(4))) float f32x4;

#define MFMA16 __builtin_amdgcn_mfma_f32_16x16x32_bf16

__device__ __forceinline__ short f2bf(float f) {
  union { float f; unsigned u; } x;
  x.f = f;
  unsigned r = x.u + 0x7FFFu + ((x.u >> 16) & 1u);
  return (short)(r >> 16);
}

// ---------------------------------------------------------------------------
// x [n] fp32 -> bf16 (as short), 8 elems/thread
// ---------------------------------------------------------------------------
__global__ __launch_bounds__(256) void cast_f32_bf16(
    const float* __restrict__ s, short* __restrict__ d, int n) {
  const int i = (blockIdx.x * 256 + threadIdx.x) * 8;
  if (i >= n) return;
  const float4 a = *reinterpret_cast<const float4*>(&s[i]);
  const float4 b = *reinterpret_cast<const float4*>(&s[i + 4]);
  short8 o;
  o[0] = f2bf(a.x); o[1] = f2bf(a.y); o[2] = f2bf(a.z); o[3] = f2bf(a.w);
  o[4] = f2bf(b.x); o[5] = f2bf(b.y); o[6] = f2bf(b.z); o[7] = f2bf(b.w);
  *reinterpret_cast<short8*>(&d[i]) = o;
}

// ---------------------------------------------------------------------------
// W [K,N] fp32 -> Wt [N,K] bf16, 64x64 tiles through LDS
// ---------------------------------------------------------------------------
__global__ __launch_bounds__(256) void transpose_cast_bf16(
    const float* __restrict__ W, short* __restrict__ Wt, int K, int N) {
  __shared__ __align__(16) float Ls[64][68];
  const int n0 = blockIdx.x * 64, k0 = blockIdx.y * 64;
  const int tid = threadIdx.x;
  {
    const int r = tid >> 4, c4 = (tid & 15) * 4;
#pragma unroll
    for (int p = 0; p < 4; ++p) {
      const float4 v = *reinterpret_cast<const float4*>(
          &W[(size_t)(k0 + r + p * 16) * N + n0 + c4]);
      *reinterpret_cast<float4*>(&Ls[r + p * 16][c4]) = v;
    }
  }
  __syncthreads();
  {
    const int n = tid >> 2;
    const int kk0 = (tid & 3) * 16;
#pragma unroll
    for (int half = 0; half < 2; ++half) {
      short8 o;
#pragma unroll
      for (int t = 0; t < 8; ++t) o[t] = f2bf(Ls[kk0 + half * 8 + t][n]);
      *reinterpret_cast<short8*>(&Wt[(size_t)(n0 + n) * K + k0 + kk0 + half * 8]) = o;
    }
  }
}

// ---------------------------------------------------------------------------
// v slice of qkv -> vT[b][h][d][s]  (bf16), 64x64 tiles through LDS
// ---------------------------------------------------------------------------
__global__ __launch_bounds__(256) void transpose_v(
    const short* __restrict__ qkv, short* __restrict__ vT) {
  __shared__ __align__(16) short Ls[64][72];
  const int s0 = blockIdx.x * 64;
  const int bh = blockIdx.y, b = bh >> 4, h = bh & 15;
  const int tid = threadIdx.x;
  const int r = tid >> 3, c = (tid & 7) * 8;
#pragma unroll
  for (int p = 0; p < 2; ++p) {
    *reinterpret_cast<short8*>(&Ls[r + p * 32][c]) =
        *reinterpret_cast<const short8*>(
            &qkv[(size_t)(b * TT + s0 + r + p * 32) * (3 * CC) + 2 * CC +
                 h * HD + c]);
  }
  __syncthreads();
  const int d = tid >> 2, ss = (tid & 3) * 16;
  short8 o0, o1;
#pragma unroll
  for (int t = 0; t < 8; ++t) { o0[t] = Ls[ss + t][d]; o1[t] = Ls[ss + 8 + t][d]; }
  short* dst = &vT[((size_t)(bh * HD + d)) * TT + s0 + ss];
  *reinterpret_cast<short8*>(dst) = o0;
  *reinterpret_cast<short8*>(dst + 8) = o1;
}

// ---------------------------------------------------------------------------
// GEMM (m97 structure): C[M,N] = A[M,K] * Bt[N,K]^T + bias
// ---------------------------------------------------------------------------
template <bool OUT_BF16>
__global__ __launch_bounds__(256) void gemm_bt_mfma(
    const short* __restrict__ A, const short* __restrict__ Bt,
    const float* __restrict__ bias, void* __restrict__ C, int M, int N, int K) {
  __shared__ __align__(16) short As[128 * 32];
  __shared__ __align__(16) short Bs[128 * 32];
  const int tid = threadIdx.x;
  const int w = tid >> 6, lane = tid & 63;
  const int quad = lane >> 4, l15 = lane & 15;
  const int m0 = blockIdx.y * 128, n0 = blockIdx.x * 128;
  const int wm = (w >> 1) * 64, wn = (w & 1) * 64;

  f32x4 acc[4][4] = {};
  const int srow = lane >> 2;
  const int scol = (lane & 3) * 8;

  for (int k0 = 0; k0 < K; k0 += 32) {
    __syncthreads();
#pragma unroll
    for (int p = 0; p < 2; ++p) {
      const int rb = __builtin_amdgcn_readfirstlane((w * 2 + p) * 16);
      const short* ga = &A[(size_t)(m0 + rb + srow) * K + k0 + scol];
      const short* gb = &Bt[(size_t)(n0 + rb + srow) * K + k0 + scol];
      __builtin_amdgcn_global_load_lds(
          (const __attribute__((address_space(1))) void*)ga,
          (__attribute__((address_space(3))) void*)&As[rb * 32], 16, 0, 0);
      __builtin_amdgcn_global_load_lds(
          (const __attribute__((address_space(1))) void*)gb,
          (__attribute__((address_space(3))) void*)&Bs[rb * 32], 16, 0, 0);
    }
    __syncthreads();

    short8 af[4], bfr[4];
#pragma unroll
    for (int i = 0; i < 4; ++i)
      af[i] = *reinterpret_cast<const short8*>(
          &As[(wm + i * 16 + l15) * 32 + quad * 8]);
#pragma unroll
    for (int j = 0; j < 4; ++j)
      bfr[j] = *reinterpret_cast<const short8*>(
          &Bs[(wn + j * 16 + l15) * 32 + quad * 8]);
#pragma unroll
    for (int i = 0; i < 4; ++i)
#pragma unroll
      for (int j = 0; j < 4; ++j)
        acc[i][j] = MFMA16(af[i], bfr[j], acc[i][j], 0, 0, 0);
  }

#pragma unroll
  for (int i = 0; i < 4; ++i) {
#pragma unroll
    for (int r = 0; r < 4; ++r) {
      const int row = m0 + wm + i * 16 + quad * 4 + r;
#pragma unroll
      for (int j = 0; j < 4; ++j) {
        const int col = n0 + wn + j * 16 + l15;
        const float v = acc[i][j][r] + bias[col];
        if (OUT_BF16)
          ((short*)C)[(size_t)row * N + col] = f2bf(v);
        else
          ((float*)C)[(size_t)row * N + col] = v;
      }
    }
  }
}

// ---------------------------------------------------------------------------
// MFMA flash attention v3: 512 threads = 8 waves, 1 strip (16 q rows)/wave,
// BQ=128 per block. S^T = K Q^T; vectorized P path; causal fast-path.
// Grid: (T/128, B*NH).
// ---------------------------------------------------------------------------
#define PST 72
__global__ __launch_bounds__(512) void attn_mfma3(
    const short* __restrict__ qkv, const short* __restrict__ vT,
    const float* __restrict__ mask, short* __restrict__ y) {
  __shared__ __align__(16) short Ks[64 * PST];
  __shared__ __align__(16) short Vs[64 * PST];   // V^T tile [d][s]
  __shared__ __align__(16) short Ps[128 * PST];  // P [q_local][s]
  const int tid = threadIdx.x;
  const int w = tid >> 6, lane = tid & 63;
  const int quad = lane >> 4, l15 = lane & 15;
  const int bh = blockIdx.y, b = bh >> 4, h = bh & 15;
  const int qi = gridDim.x - 1 - blockIdx.x;  // heavy blocks first
  const int q0 = qi * 128;
  const int RS = 3 * CC;
  const int qrow0 = q0 + w * 16;  // this wave's strip start (global q)

  // Q fragments in registers (B-operand), loaded once
  short8 qf0, qf1;
  {
    const size_t qrow = (size_t)(b * TT + qrow0 + l15) * RS + h * HD + quad * 8;
    qf0 = *reinterpret_cast<const short8*>(&qkv[qrow]);
    qf1 = *reinterpret_cast<const short8*>(&qkv[qrow + 32]);
  }

  float m_run = -1e30f, l_run = 0.f;
  f32x4 o_acc[4] = {};

  const int nt = 2 * qi + 2;
  // staging: 512 threads cover 64x64 tile (one short8 each)
  const int sr = tid >> 3, sc = (tid & 7) * 8;
  const short* kptr = qkv + (size_t)(b * TT + sr) * RS + CC + h * HD + sc;
  const short* vptr = vT + (size_t)(bh * HD + sr) * TT + sc;
  const float* mptr = mask + b * TT + quad * 4;
  const size_t kstride = (size_t)64 * RS;

  short* psrow = &Ps[(w * 16 + l15) * PST];  // this lane's P row base
  const int kfo0 = quad * 8, kfo1 = 32 + quad * 8;

  for (int kt = 0; kt < nt; ++kt) {
    const int s0 = kt * 64;
    __syncthreads();  // prior iteration's LDS reads complete
    *reinterpret_cast<short8*>(&Ks[sr * PST + sc]) =
        *reinterpret_cast<const short8*>(kptr);
    *reinterpret_cast<short8*>(&Vs[sr * PST + sc]) =
        *reinterpret_cast<const short8*>(vptr);
    kptr += kstride;
    vptr += 64;
    __syncthreads();  // K/V staged

    if (s0 > qrow0 + 15) continue;  // fully masked for this strip (wave-uniform)

    // S^T = K Q^T : 16 q cols (l15), 64 key rows (j*16+quad*4+r)
    f32x4 sa[4] = {};
#pragma unroll
    for (int j = 0; j < 4; ++j) {
      const short8 kf0 = *reinterpret_cast<const short8*>(
          &Ks[(j * 16 + l15) * PST + kfo0]);
      const short8 kf1 = *reinterpret_cast<const short8*>(
          &Ks[(j * 16 + l15) * PST + kfo1]);
      sa[j] = MFMA16(kf0, qf0, sa[j], 0, 0, 0);
      sa[j] = MFMA16(kf1, qf1, sa[j], 0, 0, 0);
    }

    // mask values (consecutive s per lane reg)
    f32x4 mv[4];
#pragma unroll
    for (int j = 0; j < 4; ++j)
      mv[j] = *reinterpret_cast<const f32x4*>(&mptr[s0 + j * 16]);

    float mx = -1e30f;
    if (s0 + 63 > qrow0) {
      // boundary tile: apply causal compare
      const int qg = qrow0 + l15;
#pragma unroll
      for (int j = 0; j < 4; ++j) {
#pragma unroll
        for (int r = 0; r < 4; ++r) {
          const int sg = s0 + j * 16 + quad * 4 + r;
          float v = (sg > qg) ? -10000.0f : sa[j][r] * 0.125f;
          v += mv[j][r];
          sa[j][r] = v;
          mx = fmaxf(mx, v);
        }
      }
    } else {
      // interior tile: no causal masking needed
#pragma unroll
      for (int j = 0; j < 4; ++j) {
#pragma unroll
        for (int r = 0; r < 4; ++r) {
          const float v = sa[j][r] * 0.125f + mv[j][r];
          sa[j][r] = v;
          mx = fmaxf(mx, v);
        }
      }
    }
    mx = fmaxf(mx, __shfl_xor(mx, 16, 64));
    mx = fmaxf(mx, __shfl_xor(mx, 32, 64));
    const float mn = fmaxf(m_run, mx);
    const float alpha = __expf(m_run - mn);
    m_run = mn;

    float rs = 0.f;
#pragma unroll
    for (int j = 0; j < 4; ++j) {
      sh4 pw;
#pragma unroll
      for (int r = 0; r < 4; ++r) {
        const float p = __expf(sa[j][r] - mn);
        rs += p;
        pw[r] = f2bf(p);
      }
      *reinterpret_cast<sh4*>(&psrow[j * 16 + quad * 4]) = pw;
    }
    rs += __shfl_xor(rs, 16, 64);
    rs += __shfl_xor(rs, 32, 64);
    l_run = l_run * alpha + rs;

    // rescale O rows (alpha for row quad*4+r lives at lane quad*4+r)
#pragma unroll
    for (int r = 0; r < 4; ++r) {
      const float ar = __shfl(alpha, quad * 4 + r, 64);
#pragma unroll
      for (int t = 0; t < 4; ++t) o_acc[t][r] *= ar;
    }

    // O += P V  (P rows owned by this wave; intra-wave LDS ordering)
    const short8 pf0 = *reinterpret_cast<const short8*>(&psrow[kfo0]);
    const short8 pf1 = *reinterpret_cast<const short8*>(&psrow[kfo1]);
#pragma unroll
    for (int t = 0; t < 4; ++t) {
      const short8 vf0 = *reinterpret_cast<const short8*>(
          &Vs[(t * 16 + l15) * PST + kfo0]);
      const short8 vf1 = *reinterpret_cast<const short8*>(
          &Vs[(t * 16 + l15) * PST + kfo1]);
      o_acc[t] = MFMA16(pf0, vf0, o_acc[t], 0, 0, 0);
      o_acc[t] = MFMA16(pf1, vf1, o_acc[t], 0, 0, 0);
    }
  }

  // epilogue: O lane layout q=quad*4+r (row), d=t*16+l15 (col)
#pragma unroll
  for (int r = 0; r < 4; ++r) {
    const float lr = __shfl(l_run, quad * 4 + r, 64);
    const float inv = 1.0f / lr;
    const size_t row = (size_t)(b * TT + qrow0 + quad * 4 + r);
#pragma unroll
    for (int t = 0; t < 4; ++t)
      y[row * CC + h * HD + t * 16 + l15] = f2bf(o_acc[t][r] * inv);
  }
}

extern "C" void kernel_launch(void* const* d_in, const int* in_sizes, int n_in,
                              void* d_out, int out_size, void* d_ws,
                              size_t ws_size, hipStream_t stream) {
  const float* x = (const float*)d_in[0];
  const float* attn_mask = (const float*)d_in[1];
  const float* W_attn = (const float*)d_in[2];
  const float* b_attn = (const float*)d_in[3];
  const float* W_proj = (const float*)d_in[4];
  const float* b_proj = (const float*)d_in[5];
  float* out = (float*)d_out;

  const int M = BATCH * TT;  // 4096

  short* xb = (short*)d_ws;                       // [4096,1024]
  short* wat = xb + (size_t)M * CC;               // [3072,1024]
  short* wpt = wat + (size_t)(3 * CC) * CC;       // [1024,1024]
  short* qkvb = wpt + (size_t)CC * CC;            // [4096,3072]
  short* yb = qkvb + (size_t)M * 3 * CC;          // [4096,1024]
  short* vTb = yb + (size_t)M * CC;               // [2*16*64, 2048]

  cast_f32_bf16<<<(M * CC) / (256 * 8), 256, 0, stream>>>(x, xb, M * CC);
  transpose_cast_bf16<<<dim3((3 * CC) / 64, CC / 64), 256, 0, stream>>>(
      W_attn, wat, CC, 3 * CC);
  transpose_cast_bf16<<<dim3(CC / 64, CC / 64), 256, 0, stream>>>(
      W_proj, wpt, CC, CC);

  gemm_bt_mfma<true><<<dim3((3 * CC) / 128, M / 128), 256, 0, stream>>>(
      xb, wat, b_attn, qkvb, M, 3 * CC, CC);

  transpose_v<<<dim3(TT / 64, BATCH * NH), 256, 0, stream>>>(qkvb, vTb);

  attn_mfma3<<<dim3(TT / 128, BATCH * NH), 512, 0, stream>>>(
      qkvb, vTb, attn_mask, yb);

  gemm_bt_mfma<false><<<dim3(CC / 128, M / 128), 256, 0, stream>>>(
      yb, wpt, b_proj, out, M, CC, CC);
}

// Round 6
// 222.006 us; speedup vs baseline: 4.6784x; 1.0808x over previous
//
#include <hip/hip_runtime.h>
#include <hip/hip_bf16.h>
#include <stdint.h>

#define BATCH 2
#define TT 2048
#define CC 1024
#define NH 16
#define HD 64

typedef __attribute__((ext_vector_type(8))) short short8;
typedef __attribute__((ext_vector_type(4))) short sh4;
typedef __attribute__((ext_vector_type(4))) float f32x4;

#define MFMA16 __builtin_amdgcn_mfma_f32_16x16x32_bf16

__device__ __forceinline__ short f2bf(float f) {
  union { float f; unsigned u; } x;
  x.f = f;
  unsigned r = x.u + 0x7FFFu + ((x.u >> 16) & 1u);
  return (short)(r >> 16);
}

// ---------------------------------------------------------------------------
// x [n] fp32 -> bf16 (as short), 8 elems/thread
// ---------------------------------------------------------------------------
__global__ __launch_bounds__(256) void cast_f32_bf16(
    const float* __restrict__ s, short* __restrict__ d, int n) {
  const int i = (blockIdx.x * 256 + threadIdx.x) * 8;
  if (i >= n) return;
  const float4 a = *reinterpret_cast<const float4*>(&s[i]);
  const float4 b = *reinterpret_cast<const float4*>(&s[i + 4]);
  short8 o;
  o[0] = f2bf(a.x); o[1] = f2bf(a.y); o[2] = f2bf(a.z); o[3] = f2bf(a.w);
  o[4] = f2bf(b.x); o[5] = f2bf(b.y); o[6] = f2bf(b.z); o[7] = f2bf(b.w);
  *reinterpret_cast<short8*>(&d[i]) = o;
}

// ---------------------------------------------------------------------------
// W [K,N] fp32 -> Wt [N,K] bf16, 64x64 tiles through LDS
// ---------------------------------------------------------------------------
__global__ __launch_bounds__(256) void transpose_cast_bf16(
    const float* __restrict__ W, short* __restrict__ Wt, int K, int N) {
  __shared__ __align__(16) float Ls[64][68];
  const int n0 = blockIdx.x * 64, k0 = blockIdx.y * 64;
  const int tid = threadIdx.x;
  {
    const int r = tid >> 4, c4 = (tid & 15) * 4;
#pragma unroll
    for (int p = 0; p < 4; ++p) {
      const float4 v = *reinterpret_cast<const float4*>(
          &W[(size_t)(k0 + r + p * 16) * N + n0 + c4]);
      *reinterpret_cast<float4*>(&Ls[r + p * 16][c4]) = v;
    }
  }
  __syncthreads();
  {
    const int n = tid >> 2;
    const int kk0 = (tid & 3) * 16;
#pragma unroll
    for (int half = 0; half < 2; ++half) {
      short8 o;
#pragma unroll
      for (int t = 0; t < 8; ++t) o[t] = f2bf(Ls[kk0 + half * 8 + t][n]);
      *reinterpret_cast<short8*>(&Wt[(size_t)(n0 + n) * K + k0 + kk0 + half * 8]) = o;
    }
  }
}

// ---------------------------------------------------------------------------
// v slice of qkv -> vT[b][h][d][s]  (bf16), 64x64 tiles through LDS
// ---------------------------------------------------------------------------
__global__ __launch_bounds__(256) void transpose_v(
    const short* __restrict__ qkv, short* __restrict__ vT) {
  __shared__ __align__(16) short Ls[64][72];
  const int s0 = blockIdx.x * 64;
  const int bh = blockIdx.y, b = bh >> 4, h = bh & 15;
  const int tid = threadIdx.x;
  const int r = tid >> 3, c = (tid & 7) * 8;
#pragma unroll
  for (int p = 0; p < 2; ++p) {
    *reinterpret_cast<short8*>(&Ls[r + p * 32][c]) =
        *reinterpret_cast<const short8*>(
            &qkv[(size_t)(b * TT + s0 + r + p * 32) * (3 * CC) + 2 * CC +
                 h * HD + c]);
  }
  __syncthreads();
  const int d = tid >> 2, ss = (tid & 3) * 16;
  short8 o0, o1;
#pragma unroll
  for (int t = 0; t < 8; ++t) { o0[t] = Ls[ss + t][d]; o1[t] = Ls[ss + 8 + t][d]; }
  short* dst = &vT[((size_t)(bh * HD + d)) * TT + s0 + ss];
  *reinterpret_cast<short8*>(dst) = o0;
  *reinterpret_cast<short8*>(dst + 8) = o1;
}

// ---------------------------------------------------------------------------
// GEMM (m97 structure): C[M,N] = A[M,K] * Bt[N,K]^T + bias
// ---------------------------------------------------------------------------
template <bool OUT_BF16>
__global__ __launch_bounds__(256) void gemm_bt_mfma(
    const short* __restrict__ A, const short* __restrict__ Bt,
    const float* __restrict__ bias, void* __restrict__ C, int M, int N, int K) {
  __shared__ __align__(16) short As[128 * 32];
  __shared__ __align__(16) short Bs[128 * 32];
  const int tid = threadIdx.x;
  const int w = tid >> 6, lane = tid & 63;
  const int quad = lane >> 4, l15 = lane & 15;
  const int m0 = blockIdx.y * 128, n0 = blockIdx.x * 128;
  const int wm = (w >> 1) * 64, wn = (w & 1) * 64;

  f32x4 acc[4][4] = {};
  const int srow = lane >> 2;
  const int scol = (lane & 3) * 8;

  for (int k0 = 0; k0 < K; k0 += 32) {
    __syncthreads();
#pragma unroll
    for (int p = 0; p < 2; ++p) {
      const int rb = __builtin_amdgcn_readfirstlane((w * 2 + p) * 16);
      const short* ga = &A[(size_t)(m0 + rb + srow) * K + k0 + scol];
      const short* gb = &Bt[(size_t)(n0 + rb + srow) * K + k0 + scol];
      __builtin_amdgcn_global_load_lds(
          (const __attribute__((address_space(1))) void*)ga,
          (__attribute__((address_space(3))) void*)&As[rb * 32], 16, 0, 0);
      __builtin_amdgcn_global_load_lds(
          (const __attribute__((address_space(1))) void*)gb,
          (__attribute__((address_space(3))) void*)&Bs[rb * 32], 16, 0, 0);
    }
    __syncthreads();

    short8 af[4], bfr[4];
#pragma unroll
    for (int i = 0; i < 4; ++i)
      af[i] = *reinterpret_cast<const short8*>(
          &As[(wm + i * 16 + l15) * 32 + quad * 8]);
#pragma unroll
    for (int j = 0; j < 4; ++j)
      bfr[j] = *reinterpret_cast<const short8*>(
          &Bs[(wn + j * 16 + l15) * 32 + quad * 8]);
#pragma unroll
    for (int i = 0; i < 4; ++i)
#pragma unroll
      for (int j = 0; j < 4; ++j)
        acc[i][j] = MFMA16(af[i], bfr[j], acc[i][j], 0, 0, 0);
  }

#pragma unroll
  for (int i = 0; i < 4; ++i) {
#pragma unroll
    for (int r = 0; r < 4; ++r) {
      const int row = m0 + wm + i * 16 + quad * 4 + r;
#pragma unroll
      for (int j = 0; j < 4; ++j) {
        const int col = n0 + wn + j * 16 + l15;
        const float v = acc[i][j][r] + bias[col];
        if (OUT_BF16)
          ((short*)C)[(size_t)row * N + col] = f2bf(v);
        else
          ((float*)C)[(size_t)row * N + col] = v;
      }
    }
  }
}

// ---------------------------------------------------------------------------
// MFMA flash attention v4: diagonal-paired q-tiles (uniform 34 s-tile iters
// per block) + register-prefetch double-buffered K/V staging.
// Grid: (8, B*NH), block 512 = 8 waves; each wave 16 q rows per phase.
// Block px handles q-tile (15-px) then q-tile px.
// ---------------------------------------------------------------------------
#define PST 72
__global__ __launch_bounds__(512) void attn_mfma4(
    const short* __restrict__ qkv, const short* __restrict__ vT,
    const float* __restrict__ mask, short* __restrict__ y) {
  __shared__ __align__(16) short Ks[64 * PST];
  __shared__ __align__(16) short Vs[64 * PST];   // V^T tile [d][s]
  __shared__ __align__(16) short Ps[128 * PST];  // P [q_local][s]
  const int tid = threadIdx.x;
  const int w = tid >> 6, lane = tid & 63;
  const int quad = lane >> 4, l15 = lane & 15;
  const int bh = blockIdx.y, b = bh >> 4, h = bh & 15;
  const int px = blockIdx.x;          // 0..7
  const int qh = 15 - px;             // heavy q-tile index
  const int nth = 2 * qh + 2;         // s-tiles for heavy phase
  const int ntl = 2 * px + 2;         // s-tiles for light phase
  const int ntot = nth + ntl;         // == 34, uniform
  const int RS = 3 * CC;

  int qrow0 = qh * 128 + w * 16;      // this wave's strip start (global q)

  // Q fragments (B-operand), reloaded at phase switch
  short8 qf0, qf1;
  {
    const size_t qrow = (size_t)(b * TT + qrow0 + l15) * RS + h * HD + quad * 8;
    qf0 = *reinterpret_cast<const short8*>(&qkv[qrow]);
    qf1 = *reinterpret_cast<const short8*>(&qkv[qrow + 32]);
  }

  float m_run = -1e30f, l_run = 0.f;
  f32x4 o_acc[4] = {};

  // staging: 512 threads cover 64x64 tile (one short8 each)
  const int sr = tid >> 3, sc = (tid & 7) * 8;
  const short* kbase = qkv + (size_t)(b * TT + sr) * RS + CC + h * HD + sc;
  const short* vbase = vT + (size_t)(bh * HD + sr) * TT + sc;
  const float* mptr = mask + b * TT + quad * 4;
  short* psrow = &Ps[(w * 16 + l15) * PST];
  const int kfo0 = quad * 8, kfo1 = 32 + quad * 8;

  // prefetch s-tile 0
  short8 kpre = *reinterpret_cast<const short8*>(kbase);
  short8 vpre = *reinterpret_cast<const short8*>(vbase);

  for (int it = 0; it < ntot; ++it) {
    const bool second = (it >= nth);
    const int kt = second ? it - nth : it;
    const int s0 = kt * 64;

    if (it == nth) {
      // flush heavy-phase output, reset state for light q-tile
#pragma unroll
      for (int r = 0; r < 4; ++r) {
        const float lr = __shfl(l_run, quad * 4 + r, 64);
        const float inv = 1.0f / lr;
        const size_t row = (size_t)(b * TT + qrow0 + quad * 4 + r);
#pragma unroll
        for (int t = 0; t < 4; ++t)
          y[row * CC + h * HD + t * 16 + l15] = f2bf(o_acc[t][r] * inv);
      }
      qrow0 = px * 128 + w * 16;
      const size_t qrow = (size_t)(b * TT + qrow0 + l15) * RS + h * HD + quad * 8;
      qf0 = *reinterpret_cast<const short8*>(&qkv[qrow]);
      qf1 = *reinterpret_cast<const short8*>(&qkv[qrow + 32]);
      m_run = -1e30f;
      l_run = 0.f;
#pragma unroll
      for (int t = 0; t < 4; ++t) o_acc[t] = f32x4{0.f, 0.f, 0.f, 0.f};
    }

    __syncthreads();  // prior iteration's LDS reads complete
    *reinterpret_cast<short8*>(&Ks[sr * PST + sc]) = kpre;
    *reinterpret_cast<short8*>(&Vs[sr * PST + sc]) = vpre;
    __syncthreads();  // K/V staged

    // prefetch next tile (global latency hides behind compute below)
    if (it + 1 < ntot) {
      const int ktn = (it + 1 == nth) ? 0 : kt + 1;
      kpre = *reinterpret_cast<const short8*>(kbase + (size_t)ktn * 64 * RS);
      vpre = *reinterpret_cast<const short8*>(vbase + ktn * 64);
    }

    if (s0 > qrow0 + 15) continue;  // fully masked for this strip (wave-uniform)

    // S^T = K Q^T : 16 q cols (l15), 64 key rows (j*16+quad*4+r)
    f32x4 sa[4] = {};
#pragma unroll
    for (int j = 0; j < 4; ++j) {
      const short8 kf0 = *reinterpret_cast<const short8*>(
          &Ks[(j * 16 + l15) * PST + kfo0]);
      const short8 kf1 = *reinterpret_cast<const short8*>(
          &Ks[(j * 16 + l15) * PST + kfo1]);
      sa[j] = MFMA16(kf0, qf0, sa[j], 0, 0, 0);
      sa[j] = MFMA16(kf1, qf1, sa[j], 0, 0, 0);
    }

    f32x4 mv[4];
#pragma unroll
    for (int j = 0; j < 4; ++j)
      mv[j] = *reinterpret_cast<const f32x4*>(&mptr[s0 + j * 16]);

    float mx = -1e30f;
    if (s0 + 63 > qrow0) {
      const int qg = qrow0 + l15;
#pragma unroll
      for (int j = 0; j < 4; ++j) {
#pragma unroll
        for (int r = 0; r < 4; ++r) {
          const int sg = s0 + j * 16 + quad * 4 + r;
          float v = (sg > qg) ? -10000.0f : sa[j][r] * 0.125f;
          v += mv[j][r];
          sa[j][r] = v;
          mx = fmaxf(mx, v);
        }
      }
    } else {
#pragma unroll
      for (int j = 0; j < 4; ++j) {
#pragma unroll
        for (int r = 0; r < 4; ++r) {
          const float v = sa[j][r] * 0.125f + mv[j][r];
          sa[j][r] = v;
          mx = fmaxf(mx, v);
        }
      }
    }
    mx = fmaxf(mx, __shfl_xor(mx, 16, 64));
    mx = fmaxf(mx, __shfl_xor(mx, 32, 64));
    const float mn = fmaxf(m_run, mx);
    const float alpha = __expf(m_run - mn);
    m_run = mn;

    float rs = 0.f;
#pragma unroll
    for (int j = 0; j < 4; ++j) {
      sh4 pw;
#pragma unroll
      for (int r = 0; r < 4; ++r) {
        const float p = __expf(sa[j][r] - mn);
        rs += p;
        pw[r] = f2bf(p);
      }
      *reinterpret_cast<sh4*>(&psrow[j * 16 + quad * 4]) = pw;
    }
    rs += __shfl_xor(rs, 16, 64);
    rs += __shfl_xor(rs, 32, 64);
    l_run = l_run * alpha + rs;

#pragma unroll
    for (int r = 0; r < 4; ++r) {
      const float ar = __shfl(alpha, quad * 4 + r, 64);
#pragma unroll
      for (int t = 0; t < 4; ++t) o_acc[t][r] *= ar;
    }

    // O += P V  (P rows owned by this wave; intra-wave LDS ordering)
    const short8 pf0 = *reinterpret_cast<const short8*>(&psrow[kfo0]);
    const short8 pf1 = *reinterpret_cast<const short8*>(&psrow[kfo1]);
#pragma unroll
    for (int t = 0; t < 4; ++t) {
      const short8 vf0 = *reinterpret_cast<const short8*>(
          &Vs[(t * 16 + l15) * PST + kfo0]);
      const short8 vf1 = *reinterpret_cast<const short8*>(
          &Vs[(t * 16 + l15) * PST + kfo1]);
      o_acc[t] = MFMA16(pf0, vf0, o_acc[t], 0, 0, 0);
      o_acc[t] = MFMA16(pf1, vf1, o_acc[t], 0, 0, 0);
    }
  }

  // flush light-phase output
#pragma unroll
  for (int r = 0; r < 4; ++r) {
    const float lr = __shfl(l_run, quad * 4 + r, 64);
    const float inv = 1.0f / lr;
    const size_t row = (size_t)(b * TT + qrow0 + quad * 4 + r);
#pragma unroll
    for (int t = 0; t < 4; ++t)
      y[row * CC + h * HD + t * 16 + l15] = f2bf(o_acc[t][r] * inv);
  }
}

extern "C" void kernel_launch(void* const* d_in, const int* in_sizes, int n_in,
                              void* d_out, int out_size, void* d_ws,
                              size_t ws_size, hipStream_t stream) {
  const float* x = (const float*)d_in[0];
  const float* attn_mask = (const float*)d_in[1];
  const float* W_attn = (const float*)d_in[2];
  const float* b_attn = (const float*)d_in[3];
  const float* W_proj = (const float*)d_in[4];
  const float* b_proj = (const float*)d_in[5];
  float* out = (float*)d_out;

  const int M = BATCH * TT;  // 4096

  short* xb = (short*)d_ws;                       // [4096,1024]
  short* wat = xb + (size_t)M * CC;               // [3072,1024]
  short* wpt = wat + (size_t)(3 * CC) * CC;       // [1024,1024]
  short* qkvb = wpt + (size_t)CC * CC;            // [4096,3072]
  short* yb = qkvb + (size_t)M * 3 * CC;          // [4096,1024]
  short* vTb = yb + (size_t)M * CC;               // [2*16*64, 2048]

  cast_f32_bf16<<<(M * CC) / (256 * 8), 256, 0, stream>>>(x, xb, M * CC);
  transpose_cast_bf16<<<dim3((3 * CC) / 64, CC / 64), 256, 0, stream>>>(
      W_attn, wat, CC, 3 * CC);
  transpose_cast_bf16<<<dim3(CC / 64, CC / 64), 256, 0, stream>>>(
      W_proj, wpt, CC, CC);

  gemm_bt_mfma<true><<<dim3((3 * CC) / 128, M / 128), 256, 0, stream>>>(
      xb, wat, b_attn, qkvb, M, 3 * CC, CC);

  transpose_v<<<dim3(TT / 64, BATCH * NH), 256, 0, stream>>>(qkvb, vTb);

  attn_mfma4<<<dim3(8, BATCH * NH), 512, 0, stream>>>(
      qkvb, vTb, attn_mask, yb);

  gemm_bt_mfma<false><<<dim3(CC / 128, M / 128), 256, 0, stream>>>(
      yb, wpt, b_proj, out, M, CC, CC);
}

// Round 7
// 217.948 us; speedup vs baseline: 4.7655x; 1.0186x over previous
//
#include <hip/hip_runtime.h>
#include <hip/hip_bf16.h>
#include <stdint.h>

#define BATCH 2
#define TT 2048
#define CC 1024
#define NH 16
#define HD 64

typedef __attribute__((ext_vector_type(8))) short short8;
typedef __attribute__((ext_vector_type(4))) short sh4;
typedef __attribute__((ext_vector_type(4))) float f32x4;

#define MFMA16 __builtin_amdgcn_mfma_f32_16x16x32_bf16

__device__ __forceinline__ short f2bf(float f) {
  union { float f; unsigned u; } x;
  x.f = f;
  unsigned r = x.u + 0x7FFFu + ((x.u >> 16) & 1u);
  return (short)(r >> 16);
}

// ---------------------------------------------------------------------------
// x [n] fp32 -> bf16 (as short), 8 elems/thread
// ---------------------------------------------------------------------------
__global__ __launch_bounds__(256) void cast_f32_bf16(
    const float* __restrict__ s, short* __restrict__ d, int n) {
  const int i = (blockIdx.x * 256 + threadIdx.x) * 8;
  if (i >= n) return;
  const float4 a = *reinterpret_cast<const float4*>(&s[i]);
  const float4 b = *reinterpret_cast<const float4*>(&s[i + 4]);
  short8 o;
  o[0] = f2bf(a.x); o[1] = f2bf(a.y); o[2] = f2bf(a.z); o[3] = f2bf(a.w);
  o[4] = f2bf(b.x); o[5] = f2bf(b.y); o[6] = f2bf(b.z); o[7] = f2bf(b.w);
  *reinterpret_cast<short8*>(&d[i]) = o;
}

// ---------------------------------------------------------------------------
// W [K,N] fp32 -> Wt [N,K] bf16, 64x64 tiles through LDS
// ---------------------------------------------------------------------------
__global__ __launch_bounds__(256) void transpose_cast_bf16(
    const float* __restrict__ W, short* __restrict__ Wt, int K, int N) {
  __shared__ __align__(16) float Ls[64][68];
  const int n0 = blockIdx.x * 64, k0 = blockIdx.y * 64;
  const int tid = threadIdx.x;
  {
    const int r = tid >> 4, c4 = (tid & 15) * 4;
#pragma unroll
    for (int p = 0; p < 4; ++p) {
      const float4 v = *reinterpret_cast<const float4*>(
          &W[(size_t)(k0 + r + p * 16) * N + n0 + c4]);
      *reinterpret_cast<float4*>(&Ls[r + p * 16][c4]) = v;
    }
  }
  __syncthreads();
  {
    const int n = tid >> 2;
    const int kk0 = (tid & 3) * 16;
#pragma unroll
    for (int half = 0; half < 2; ++half) {
      short8 o;
#pragma unroll
      for (int t = 0; t < 8; ++t) o[t] = f2bf(Ls[kk0 + half * 8 + t][n]);
      *reinterpret_cast<short8*>(&Wt[(size_t)(n0 + n) * K + k0 + kk0 + half * 8]) = o;
    }
  }
}

// ---------------------------------------------------------------------------
// v slice of qkv -> vT[b][h][d][s]  (bf16), 64x64 tiles through LDS
// ---------------------------------------------------------------------------
__global__ __launch_bounds__(256) void transpose_v(
    const short* __restrict__ qkv, short* __restrict__ vT) {
  __shared__ __align__(16) short Ls[64][72];
  const int s0 = blockIdx.x * 64;
  const int bh = blockIdx.y, b = bh >> 4, h = bh & 15;
  const int tid = threadIdx.x;
  const int r = tid >> 3, c = (tid & 7) * 8;
#pragma unroll
  for (int p = 0; p < 2; ++p) {
    *reinterpret_cast<short8*>(&Ls[r + p * 32][c]) =
        *reinterpret_cast<const short8*>(
            &qkv[(size_t)(b * TT + s0 + r + p * 32) * (3 * CC) + 2 * CC +
                 h * HD + c]);
  }
  __syncthreads();
  const int d = tid >> 2, ss = (tid & 3) * 16;
  short8 o0, o1;
#pragma unroll
  for (int t = 0; t < 8; ++t) { o0[t] = Ls[ss + t][d]; o1[t] = Ls[ss + 8 + t][d]; }
  short* dst = &vT[((size_t)(bh * HD + d)) * TT + s0 + ss];
  *reinterpret_cast<short8*>(dst) = o0;
  *reinterpret_cast<short8*>(dst + 8) = o1;
}

// ---------------------------------------------------------------------------
// GEMM v2: C[M,N] = A[M,K] * Bt[N,K]^T + bias, BK=64, LDS [kh][128][32].
// Cols < QS get *0.125 (q pre-scale fold). 256 thr = 4 waves.
// ---------------------------------------------------------------------------
template <bool OUT_BF16>
__global__ __launch_bounds__(256) void gemm_bt_mfma(
    const short* __restrict__ A, const short* __restrict__ Bt,
    const float* __restrict__ bias, void* __restrict__ C, int M, int N, int K,
    int QS) {
  __shared__ __align__(16) short As[2 * 128 * 32];
  __shared__ __align__(16) short Bs[2 * 128 * 32];
  const int tid = threadIdx.x;
  const int w = tid >> 6, lane = tid & 63;
  const int quad = lane >> 4, l15 = lane & 15;
  const int m0 = blockIdx.y * 128, n0 = blockIdx.x * 128;
  const int wm = (w >> 1) * 64, wn = (w & 1) * 64;

  f32x4 acc[4][4] = {};
  const int row16 = lane >> 2;      // 0..15
  const int c4 = (lane & 3) * 8;    // 0,8,16,24 shorts within 32-short half

  for (int k0 = 0; k0 < K; k0 += 64) {
    __syncthreads();
#pragma unroll
    for (int p = 0; p < 2; ++p) {
      const int rbase = __builtin_amdgcn_readfirstlane((w * 2 + p) * 16);
#pragma unroll
      for (int kh = 0; kh < 2; ++kh) {
        const short* ga = &A[(size_t)(m0 + rbase + row16) * K + k0 + kh * 32 + c4];
        const short* gb = &Bt[(size_t)(n0 + rbase + row16) * K + k0 + kh * 32 + c4];
        __builtin_amdgcn_global_load_lds(
            (const __attribute__((address_space(1))) void*)ga,
            (__attribute__((address_space(3))) void*)&As[kh * 4096 + rbase * 32],
            16, 0, 0);
        __builtin_amdgcn_global_load_lds(
            (const __attribute__((address_space(1))) void*)gb,
            (__attribute__((address_space(3))) void*)&Bs[kh * 4096 + rbase * 32],
            16, 0, 0);
      }
    }
    __syncthreads();

    short8 af[2][4], bfr[2][4];
#pragma unroll
    for (int kh = 0; kh < 2; ++kh) {
#pragma unroll
      for (int i = 0; i < 4; ++i)
        af[kh][i] = *reinterpret_cast<const short8*>(
            &As[kh * 4096 + (wm + i * 16 + l15) * 32 + quad * 8]);
#pragma unroll
      for (int j = 0; j < 4; ++j)
        bfr[kh][j] = *reinterpret_cast<const short8*>(
            &Bs[kh * 4096 + (wn + j * 16 + l15) * 32 + quad * 8]);
    }
#pragma unroll
    for (int kh = 0; kh < 2; ++kh)
#pragma unroll
      for (int i = 0; i < 4; ++i)
#pragma unroll
        for (int j = 0; j < 4; ++j)
          acc[i][j] = MFMA16(af[kh][i], bfr[kh][j], acc[i][j], 0, 0, 0);
  }

#pragma unroll
  for (int i = 0; i < 4; ++i) {
#pragma unroll
    for (int r = 0; r < 4; ++r) {
      const int row = m0 + wm + i * 16 + quad * 4 + r;
#pragma unroll
      for (int j = 0; j < 4; ++j) {
        const int col = n0 + wn + j * 16 + l15;
        float v = acc[i][j][r] + bias[col];
        if (col < QS) v *= 0.125f;
        if (OUT_BF16)
          ((short*)C)[(size_t)row * N + col] = f2bf(v);
        else
          ((float*)C)[(size_t)row * N + col] = v;
      }
    }
  }
}

// ---------------------------------------------------------------------------
// MFMA flash attention v5: fixed-m softmax (scores bounded; q pre-scaled),
// double-buffered K/V LDS (ONE barrier per s-tile), diagonal-paired q-tiles.
// Grid: (8, B*NH), block 512 = 8 waves; block px does q-tile 15-px then px.
// ---------------------------------------------------------------------------
#define PST 72
__global__ __launch_bounds__(512) void attn_mfma5(
    const short* __restrict__ qkv, const short* __restrict__ vT,
    const float* __restrict__ mask, short* __restrict__ y) {
  __shared__ __align__(16) short Ks[2][64 * PST];
  __shared__ __align__(16) short Vs[2][64 * PST];  // V^T tile [d][s]
  __shared__ __align__(16) short Ps[128 * PST];    // P [q_local][s]
  const int tid = threadIdx.x;
  const int w = tid >> 6, lane = tid & 63;
  const int quad = lane >> 4, l15 = lane & 15;
  const int bh = blockIdx.y, b = bh >> 4, h = bh & 15;
  const int px = blockIdx.x;          // 0..7
  const int qh = 15 - px;             // heavy q-tile index
  const int nth = 2 * qh + 2;
  const int ntl = 2 * px + 2;
  const int ntot = nth + ntl;         // 34, uniform
  const int RS = 3 * CC;

  int qrow0 = qh * 128 + w * 16;

  // Q fragments (pre-scaled by 0.125 in GEMM epilogue)
  short8 qf0, qf1;
  {
    const size_t qrow = (size_t)(b * TT + qrow0 + l15) * RS + h * HD + quad * 8;
    qf0 = *reinterpret_cast<const short8*>(&qkv[qrow]);
    qf1 = *reinterpret_cast<const short8*>(&qkv[qrow + 32]);
  }

  float l_run = 0.f;
  f32x4 o_acc[4] = {};

  const int sr = tid >> 3, sc = (tid & 7) * 8;
  const short* kbase = qkv + (size_t)(b * TT + sr) * RS + CC + h * HD + sc;
  const short* vbase = vT + (size_t)(bh * HD + sr) * TT + sc;
  const float* mptr = mask + b * TT + quad * 4;
  short* psrow = &Ps[(w * 16 + l15) * PST];
  const int kfo0 = quad * 8, kfo1 = 32 + quad * 8;

  // prefetch s-tile 0 into regs
  short8 kpre = *reinterpret_cast<const short8*>(kbase);
  short8 vpre = *reinterpret_cast<const short8*>(vbase);

  for (int it = 0; it < ntot; ++it) {
    const int kt = (it >= nth) ? it - nth : it;
    const int s0 = kt * 64;

    if (it == nth) {
      // flush heavy-phase output, reset for light q-tile (regs only)
#pragma unroll
      for (int r = 0; r < 4; ++r) {
        const float lr = __shfl(l_run, quad * 4 + r, 64);
        const float inv = 1.0f / lr;
        const size_t row = (size_t)(b * TT + qrow0 + quad * 4 + r);
#pragma unroll
        for (int t = 0; t < 4; ++t)
          y[row * CC + h * HD + t * 16 + l15] = f2bf(o_acc[t][r] * inv);
      }
      qrow0 = px * 128 + w * 16;
      const size_t qrow = (size_t)(b * TT + qrow0 + l15) * RS + h * HD + quad * 8;
      qf0 = *reinterpret_cast<const short8*>(&qkv[qrow]);
      qf1 = *reinterpret_cast<const short8*>(&qkv[qrow + 32]);
      l_run = 0.f;
#pragma unroll
      for (int t = 0; t < 4; ++t) o_acc[t] = f32x4{0.f, 0.f, 0.f, 0.f};
    }

    const int cur = it & 1;
    // stage tile `it` from regs; ONE barrier per iteration.
    // Safe: last readers of buf[cur] (iter it-2) finished before barrier(it-1).
    *reinterpret_cast<short8*>(&Ks[cur][sr * PST + sc]) = kpre;
    *reinterpret_cast<short8*>(&Vs[cur][sr * PST + sc]) = vpre;
    __syncthreads();

    // prefetch tile it+1 (latency hides behind compute)
    if (it + 1 < ntot) {
      const int ktn = (it + 1 == nth) ? 0 : kt + 1;
      kpre = *reinterpret_cast<const short8*>(kbase + (size_t)ktn * 64 * RS);
      vpre = *reinterpret_cast<const short8*>(vbase + ktn * 64);
    }

    if (s0 > qrow0 + 15) continue;  // fully masked for this strip (wave-uniform)

    // S^T = K Q'^T : 16 q cols (l15), 64 key rows (j*16+quad*4+r)
    f32x4 sa[4] = {};
#pragma unroll
    for (int j = 0; j < 4; ++j) {
      const short8 kf0 = *reinterpret_cast<const short8*>(
          &Ks[cur][(j * 16 + l15) * PST + kfo0]);
      const short8 kf1 = *reinterpret_cast<const short8*>(
          &Ks[cur][(j * 16 + l15) * PST + kfo1]);
      sa[j] = MFMA16(kf0, qf0, sa[j], 0, 0, 0);
      sa[j] = MFMA16(kf1, qf1, sa[j], 0, 0, 0);
    }

    f32x4 mv[4];
#pragma unroll
    for (int j = 0; j < 4; ++j)
      mv[j] = *reinterpret_cast<const f32x4*>(&mptr[s0 + j * 16]);

    // fixed-m softmax: p = exp(s + mask); scores bounded (|s| << 80) so no
    // overflow without online max. Truncating bf16 pack; l sums truncated p.
    float rs = 0.f;
    const bool boundary = (s0 + 63 > qrow0);
    const int qg = qrow0 + l15;
#pragma unroll
    for (int j = 0; j < 4; ++j) {
      sh4 pw;
#pragma unroll
      for (int r = 0; r < 4; ++r) {
        float v = sa[j][r] + mv[j][r];
        if (boundary) {
          const int sg = s0 + j * 16 + quad * 4 + r;
          if (sg > qg) v = -10000.0f;
        }
        const float p = __expf(v);
        union { float f; unsigned u; } pu;
        pu.f = p;
        pw[r] = (short)(pu.u >> 16);
        pu.u &= 0xffff0000u;
        rs += pu.f;
      }
      *reinterpret_cast<sh4*>(&psrow[j * 16 + quad * 4]) = pw;
    }
    rs += __shfl_xor(rs, 16, 64);
    rs += __shfl_xor(rs, 32, 64);
    l_run += rs;

    // O += P V  (P rows owned by this wave; intra-wave LDS ordering)
    const short8 pf0 = *reinterpret_cast<const short8*>(&psrow[kfo0]);
    const short8 pf1 = *reinterpret_cast<const short8*>(&psrow[kfo1]);
#pragma unroll
    for (int t = 0; t < 4; ++t) {
      const short8 vf0 = *reinterpret_cast<const short8*>(
          &Vs[cur][(t * 16 + l15) * PST + kfo0]);
      const short8 vf1 = *reinterpret_cast<const short8*>(
          &Vs[cur][(t * 16 + l15) * PST + kfo1]);
      o_acc[t] = MFMA16(pf0, vf0, o_acc[t], 0, 0, 0);
      o_acc[t] = MFMA16(pf1, vf1, o_acc[t], 0, 0, 0);
    }
  }

  // flush light-phase output
#pragma unroll
  for (int r = 0; r < 4; ++r) {
    const float lr = __shfl(l_run, quad * 4 + r, 64);
    const float inv = 1.0f / lr;
    const size_t row = (size_t)(b * TT + qrow0 + quad * 4 + r);
#pragma unroll
    for (int t = 0; t < 4; ++t)
      y[row * CC + h * HD + t * 16 + l15] = f2bf(o_acc[t][r] * inv);
  }
}

extern "C" void kernel_launch(void* const* d_in, const int* in_sizes, int n_in,
                              void* d_out, int out_size, void* d_ws,
                              size_t ws_size, hipStream_t stream) {
  const float* x = (const float*)d_in[0];
  const float* attn_mask = (const float*)d_in[1];
  const float* W_attn = (const float*)d_in[2];
  const float* b_attn = (const float*)d_in[3];
  const float* W_proj = (const float*)d_in[4];
  const float* b_proj = (const float*)d_in[5];
  float* out = (float*)d_out;

  const int M = BATCH * TT;  // 4096

  short* xb = (short*)d_ws;                       // [4096,1024]
  short* wat = xb + (size_t)M * CC;               // [3072,1024]
  short* wpt = wat + (size_t)(3 * CC) * CC;       // [1024,1024]
  short* qkvb = wpt + (size_t)CC * CC;            // [4096,3072]
  short* yb = qkvb + (size_t)M * 3 * CC;          // [4096,1024]
  short* vTb = yb + (size_t)M * CC;               // [2*16*64, 2048]

  cast_f32_bf16<<<(M * CC) / (256 * 8), 256, 0, stream>>>(x, xb, M * CC);
  transpose_cast_bf16<<<dim3((3 * CC) / 64, CC / 64), 256, 0, stream>>>(
      W_attn, wat, CC, 3 * CC);
  transpose_cast_bf16<<<dim3(CC / 64, CC / 64), 256, 0, stream>>>(
      W_proj, wpt, CC, CC);

  // qkv = x @ W_attn + b_attn; q-third scaled by 0.125 (folded attn scale)
  gemm_bt_mfma<true><<<dim3((3 * CC) / 128, M / 128), 256, 0, stream>>>(
      xb, wat, b_attn, qkvb, M, 3 * CC, CC, CC);

  transpose_v<<<dim3(TT / 64, BATCH * NH), 256, 0, stream>>>(qkvb, vTb);

  attn_mfma5<<<dim3(8, BATCH * NH), 512, 0, stream>>>(
      qkvb, vTb, attn_mask, yb);

  gemm_bt_mfma<false><<<dim3(CC / 128, M / 128), 256, 0, stream>>>(
      yb, wpt, b_proj, out, M, CC, CC, 0);
}

// Round 8
// 207.379 us; speedup vs baseline: 5.0084x; 1.0510x over previous
//
#include <hip/hip_runtime.h>
#include <hip/hip_bf16.h>
#include <stdint.h>

#define BATCH 2
#define TT 2048
#define CC 1024
#define NH 16
#define HD 64

typedef __attribute__((ext_vector_type(8))) short short8;
typedef __attribute__((ext_vector_type(4))) short sh4;
typedef __attribute__((ext_vector_type(4))) float f32x4;

#define MFMA16 __builtin_amdgcn_mfma_f32_16x16x32_bf16

__device__ __forceinline__ short f2bf(float f) {
  union { float f; unsigned u; } x;
  x.f = f;
  unsigned r = x.u + 0x7FFFu + ((x.u >> 16) & 1u);
  return (short)(r >> 16);
}

// ---------------------------------------------------------------------------
// Fused prep: blocks [0,2048) cast x fp32->bf16; [2048,2816) transpose W_attn;
// [2816,3072) transpose W_proj. 256 threads.
// ---------------------------------------------------------------------------
__device__ __forceinline__ void transpose_cast_tile(
    const float* __restrict__ W, short* __restrict__ Wt, int K, int N,
    int n0, int k0, int tid) {
  __shared__ __align__(16) float Ls[64][68];
  {
    const int r = tid >> 4, c4 = (tid & 15) * 4;
#pragma unroll
    for (int p = 0; p < 4; ++p) {
      const float4 v = *reinterpret_cast<const float4*>(
          &W[(size_t)(k0 + r + p * 16) * N + n0 + c4]);
      *reinterpret_cast<float4*>(&Ls[r + p * 16][c4]) = v;
    }
  }
  __syncthreads();
  {
    const int n = tid >> 2;
    const int kk0 = (tid & 3) * 16;
#pragma unroll
    for (int half = 0; half < 2; ++half) {
      short8 o;
#pragma unroll
      for (int t = 0; t < 8; ++t) o[t] = f2bf(Ls[kk0 + half * 8 + t][n]);
      *reinterpret_cast<short8*>(&Wt[(size_t)(n0 + n) * K + k0 + kk0 + half * 8]) = o;
    }
  }
}

__global__ __launch_bounds__(256) void prep_fused(
    const float* __restrict__ x, short* __restrict__ xb,
    const float* __restrict__ W_attn, short* __restrict__ wat,
    const float* __restrict__ W_proj, short* __restrict__ wpt) {
  const int blk = blockIdx.x;
  const int tid = threadIdx.x;
  if (blk < 2048) {
    const int i = (blk * 256 + tid) * 8;
    const float4 a = *reinterpret_cast<const float4*>(&x[i]);
    const float4 b = *reinterpret_cast<const float4*>(&x[i + 4]);
    short8 o;
    o[0] = f2bf(a.x); o[1] = f2bf(a.y); o[2] = f2bf(a.z); o[3] = f2bf(a.w);
    o[4] = f2bf(b.x); o[5] = f2bf(b.y); o[6] = f2bf(b.z); o[7] = f2bf(b.w);
    *reinterpret_cast<short8*>(&xb[i]) = o;
  } else if (blk < 2816) {
    const int b2 = blk - 2048;
    transpose_cast_tile(W_attn, wat, CC, 3 * CC, (b2 % 48) * 64,
                        (b2 / 48) * 64, tid);
  } else {
    const int b3 = blk - 2816;
    transpose_cast_tile(W_proj, wpt, CC, CC, (b3 % 16) * 64, (b3 / 16) * 64,
                        tid);
  }
}

// ---------------------------------------------------------------------------
// v slice of qkv -> vT[b][h][d][s]  (bf16), 64x64 tiles through LDS
// ---------------------------------------------------------------------------
__global__ __launch_bounds__(256) void transpose_v(
    const short* __restrict__ qkv, short* __restrict__ vT) {
  __shared__ __align__(16) short Ls[64][72];
  const int s0 = blockIdx.x * 64;
  const int bh = blockIdx.y, b = bh >> 4, h = bh & 15;
  const int tid = threadIdx.x;
  const int r = tid >> 3, c = (tid & 7) * 8;
#pragma unroll
  for (int p = 0; p < 2; ++p) {
    *reinterpret_cast<short8*>(&Ls[r + p * 32][c]) =
        *reinterpret_cast<const short8*>(
            &qkv[(size_t)(b * TT + s0 + r + p * 32) * (3 * CC) + 2 * CC +
                 h * HD + c]);
  }
  __syncthreads();
  const int d = tid >> 2, ss = (tid & 3) * 16;
  short8 o0, o1;
#pragma unroll
  for (int t = 0; t < 8; ++t) { o0[t] = Ls[ss + t][d]; o1[t] = Ls[ss + 8 + t][d]; }
  short* dst = &vT[((size_t)(bh * HD + d)) * TT + s0 + ss];
  *reinterpret_cast<short8*>(dst) = o0;
  *reinterpret_cast<short8*>(dst + 8) = o1;
}

// ---------------------------------------------------------------------------
// GEMM: C[M,N] = A[M,K] * Bt[N,K]^T + bias, BK=64, LDS [kh][128][32].
// Cols < QS get *0.125 (q pre-scale fold). 256 thr = 4 waves.
// ---------------------------------------------------------------------------
template <bool OUT_BF16>
__global__ __launch_bounds__(256) void gemm_bt_mfma(
    const short* __restrict__ A, const short* __restrict__ Bt,
    const float* __restrict__ bias, void* __restrict__ C, int M, int N, int K,
    int QS) {
  __shared__ __align__(16) short As[2 * 128 * 32];
  __shared__ __align__(16) short Bs[2 * 128 * 32];
  const int tid = threadIdx.x;
  const int w = tid >> 6, lane = tid & 63;
  const int quad = lane >> 4, l15 = lane & 15;
  const int m0 = blockIdx.y * 128, n0 = blockIdx.x * 128;
  const int wm = (w >> 1) * 64, wn = (w & 1) * 64;

  f32x4 acc[4][4] = {};
  const int row16 = lane >> 2;
  const int c4 = (lane & 3) * 8;

  for (int k0 = 0; k0 < K; k0 += 64) {
    __syncthreads();
#pragma unroll
    for (int p = 0; p < 2; ++p) {
      const int rbase = __builtin_amdgcn_readfirstlane((w * 2 + p) * 16);
#pragma unroll
      for (int kh = 0; kh < 2; ++kh) {
        const short* ga = &A[(size_t)(m0 + rbase + row16) * K + k0 + kh * 32 + c4];
        const short* gb = &Bt[(size_t)(n0 + rbase + row16) * K + k0 + kh * 32 + c4];
        __builtin_amdgcn_global_load_lds(
            (const __attribute__((address_space(1))) void*)ga,
            (__attribute__((address_space(3))) void*)&As[kh * 4096 + rbase * 32],
            16, 0, 0);
        __builtin_amdgcn_global_load_lds(
            (const __attribute__((address_space(1))) void*)gb,
            (__attribute__((address_space(3))) void*)&Bs[kh * 4096 + rbase * 32],
            16, 0, 0);
      }
    }
    __syncthreads();

    short8 af[2][4], bfr[2][4];
#pragma unroll
    for (int kh = 0; kh < 2; ++kh) {
#pragma unroll
      for (int i = 0; i < 4; ++i)
        af[kh][i] = *reinterpret_cast<const short8*>(
            &As[kh * 4096 + (wm + i * 16 + l15) * 32 + quad * 8]);
#pragma unroll
      for (int j = 0; j < 4; ++j)
        bfr[kh][j] = *reinterpret_cast<const short8*>(
            &Bs[kh * 4096 + (wn + j * 16 + l15) * 32 + quad * 8]);
    }
#pragma unroll
    for (int kh = 0; kh < 2; ++kh)
#pragma unroll
      for (int i = 0; i < 4; ++i)
#pragma unroll
        for (int j = 0; j < 4; ++j)
          acc[i][j] = MFMA16(af[kh][i], bfr[kh][j], acc[i][j], 0, 0, 0);
  }

#pragma unroll
  for (int i = 0; i < 4; ++i) {
#pragma unroll
    for (int r = 0; r < 4; ++r) {
      const int row = m0 + wm + i * 16 + quad * 4 + r;
#pragma unroll
      for (int j = 0; j < 4; ++j) {
        const int col = n0 + wn + j * 16 + l15;
        float v = acc[i][j][r] + bias[col];
        if (col < QS) v *= 0.125f;
        if (OUT_BF16)
          ((short*)C)[(size_t)row * N + col] = f2bf(v);
        else
          ((float*)C)[(size_t)row * N + col] = v;
      }
    }
  }
}

// ---------------------------------------------------------------------------
// MFMA flash attention v6: 256 thr = 4 waves, 64-row q-tiles diagonal-paired
// (uniform 33 s-tile iters), grid 512 = 2 blocks/CU for cross-block overlap.
// Fixed-m softmax (q pre-scaled); single barrier/iter via dbuf K/V LDS.
// All waves active every iteration; causal branch only on the last tile of
// each phase. Grid: (16, B*NH).
// ---------------------------------------------------------------------------
#define PST 72
__global__ __launch_bounds__(256) void attn_mfma6(
    const short* __restrict__ qkv, const short* __restrict__ vT,
    const float* __restrict__ mask, short* __restrict__ y) {
  __shared__ __align__(16) short Ks[2][64 * PST];
  __shared__ __align__(16) short Vs[2][64 * PST];  // V^T tile [d][s]
  __shared__ __align__(16) short Ps[64 * PST];     // P [q_local][s]
  const int tid = threadIdx.x;
  const int w = tid >> 6, lane = tid & 63;
  const int quad = lane >> 4, l15 = lane & 15;
  const int bh = blockIdx.y, b = bh >> 4, h = bh & 15;
  const int px = blockIdx.x;          // 0..15
  const int qh = 31 - px;             // heavy q-tile (64 rows)
  const int nth = qh + 1;
  const int ntot = nth + px + 1;      // == 33, uniform
  const int RS = 3 * CC;

  int qt = qh;                        // current q-tile
  int qrow0 = qt * 64 + w * 16;

  // Q fragments (pre-scaled by 0.125 in GEMM epilogue)
  short8 qf0, qf1;
  {
    const size_t qrow = (size_t)(b * TT + qrow0 + l15) * RS + h * HD + quad * 8;
    qf0 = *reinterpret_cast<const short8*>(&qkv[qrow]);
    qf1 = *reinterpret_cast<const short8*>(&qkv[qrow + 32]);
  }

  float l_run = 0.f;
  f32x4 o_acc[4] = {};

  // staging: 256 threads, 2 rows each (sr, sr+32), one short8 per row
  const int sr = tid >> 3, sc = (tid & 7) * 8;
  const short* kbase = qkv + (size_t)(b * TT + sr) * RS + CC + h * HD + sc;
  const short* vbase = vT + (size_t)(bh * HD + sr) * TT + sc;
  const float* mptr = mask + b * TT + quad * 4;
  short* psrow = &Ps[(w * 16 + l15) * PST];
  const int kfo0 = quad * 8, kfo1 = 32 + quad * 8;

  // prefetch s-tile 0
  short8 kpre0 = *reinterpret_cast<const short8*>(kbase);
  short8 kpre1 = *reinterpret_cast<const short8*>(kbase + (size_t)32 * RS);
  short8 vpre0 = *reinterpret_cast<const short8*>(vbase);
  short8 vpre1 = *reinterpret_cast<const short8*>(vbase + 32 * TT);

  for (int it = 0; it < ntot; ++it) {
    const int kt = (it < nth) ? it : it - nth;
    const int s0 = kt * 64;

    if (it == nth) {
      // flush heavy-phase output, reset for light q-tile
#pragma unroll
      for (int r = 0; r < 4; ++r) {
        const float lr = __shfl(l_run, quad * 4 + r, 64);
        const float inv = 1.0f / lr;
        const size_t row = (size_t)(b * TT + qrow0 + quad * 4 + r);
#pragma unroll
        for (int t = 0; t < 4; ++t)
          y[row * CC + h * HD + t * 16 + l15] = f2bf(o_acc[t][r] * inv);
      }
      qt = px;
      qrow0 = qt * 64 + w * 16;
      const size_t qrow = (size_t)(b * TT + qrow0 + l15) * RS + h * HD + quad * 8;
      qf0 = *reinterpret_cast<const short8*>(&qkv[qrow]);
      qf1 = *reinterpret_cast<const short8*>(&qkv[qrow + 32]);
      l_run = 0.f;
#pragma unroll
      for (int t = 0; t < 4; ++t) o_acc[t] = f32x4{0.f, 0.f, 0.f, 0.f};
    }

    const int cur = it & 1;
    // stage tile `it`; ONE barrier per iteration (dbuf: readers of buf[cur]
    // from iter it-2 finished before barrier it-1).
    *reinterpret_cast<short8*>(&Ks[cur][sr * PST + sc]) = kpre0;
    *reinterpret_cast<short8*>(&Ks[cur][(sr + 32) * PST + sc]) = kpre1;
    *reinterpret_cast<short8*>(&Vs[cur][sr * PST + sc]) = vpre0;
    *reinterpret_cast<short8*>(&Vs[cur][(sr + 32) * PST + sc]) = vpre1;
    __syncthreads();

    // prefetch tile it+1 (hides behind compute)
    if (it + 1 < ntot) {
      const int ktn = (it + 1 == nth) ? 0 : kt + 1;
      const short* kp = kbase + (size_t)ktn * 64 * RS;
      const short* vp = vbase + ktn * 64;
      kpre0 = *reinterpret_cast<const short8*>(kp);
      kpre1 = *reinterpret_cast<const short8*>(kp + (size_t)32 * RS);
      vpre0 = *reinterpret_cast<const short8*>(vp);
      vpre1 = *reinterpret_cast<const short8*>(vp + 32 * TT);
    }

    // S^T = K Q'^T : 16 q cols (l15), 64 key rows (j*16+quad*4+r)
    f32x4 sa[4] = {};
#pragma unroll
    for (int j = 0; j < 4; ++j) {
      const short8 kf0 = *reinterpret_cast<const short8*>(
          &Ks[cur][(j * 16 + l15) * PST + kfo0]);
      const short8 kf1 = *reinterpret_cast<const short8*>(
          &Ks[cur][(j * 16 + l15) * PST + kfo1]);
      sa[j] = MFMA16(kf0, qf0, sa[j], 0, 0, 0);
      sa[j] = MFMA16(kf1, qf1, sa[j], 0, 0, 0);
    }

    f32x4 mv[4];
#pragma unroll
    for (int j = 0; j < 4; ++j)
      mv[j] = *reinterpret_cast<const f32x4*>(&mptr[s0 + j * 16]);

    // fixed-m softmax: p = exp(s + mask); scores bounded, q pre-scaled.
    float rs = 0.f;
    const bool boundary = (kt == qt);  // only the diagonal tile needs causal
    const int qg = qrow0 + l15;
#pragma unroll
    for (int j = 0; j < 4; ++j) {
      sh4 pw;
#pragma unroll
      for (int r = 0; r < 4; ++r) {
        float v = sa[j][r] + mv[j][r];
        if (boundary) {
          const int sg = s0 + j * 16 + quad * 4 + r;
          if (sg > qg) v = -10000.0f;
        }
        const float p = __expf(v);
        union { float f; unsigned u; } pu;
        pu.f = p;
        pw[r] = (short)(pu.u >> 16);
        pu.u &= 0xffff0000u;
        rs += pu.f;
      }
      *reinterpret_cast<sh4*>(&psrow[j * 16 + quad * 4]) = pw;
    }
    rs += __shfl_xor(rs, 16, 64);
    rs += __shfl_xor(rs, 32, 64);
    l_run += rs;

    // O += P V  (P rows owned by this wave; intra-wave LDS ordering)
    const short8 pf0 = *reinterpret_cast<const short8*>(&psrow[kfo0]);
    const short8 pf1 = *reinterpret_cast<const short8*>(&psrow[kfo1]);
#pragma unroll
    for (int t = 0; t < 4; ++t) {
      const short8 vf0 = *reinterpret_cast<const short8*>(
          &Vs[cur][(t * 16 + l15) * PST + kfo0]);
      const short8 vf1 = *reinterpret_cast<const short8*>(
          &Vs[cur][(t * 16 + l15) * PST + kfo1]);
      o_acc[t] = MFMA16(pf0, vf0, o_acc[t], 0, 0, 0);
      o_acc[t] = MFMA16(pf1, vf1, o_acc[t], 0, 0, 0);
    }
  }

  // flush light-phase output
#pragma unroll
  for (int r = 0; r < 4; ++r) {
    const float lr = __shfl(l_run, quad * 4 + r, 64);
    const float inv = 1.0f / lr;
    const size_t row = (size_t)(b * TT + qrow0 + quad * 4 + r);
#pragma unroll
    for (int t = 0; t < 4; ++t)
      y[row * CC + h * HD + t * 16 + l15] = f2bf(o_acc[t][r] * inv);
  }
}

extern "C" void kernel_launch(void* const* d_in, const int* in_sizes, int n_in,
                              void* d_out, int out_size, void* d_ws,
                              size_t ws_size, hipStream_t stream) {
  const float* x = (const float*)d_in[0];
  const float* attn_mask = (const float*)d_in[1];
  const float* W_attn = (const float*)d_in[2];
  const float* b_attn = (const float*)d_in[3];
  const float* W_proj = (const float*)d_in[4];
  const float* b_proj = (const float*)d_in[5];
  float* out = (float*)d_out;

  const int M = BATCH * TT;  // 4096

  short* xb = (short*)d_ws;                       // [4096,1024]
  short* wat = xb + (size_t)M * CC;               // [3072,1024]
  short* wpt = wat + (size_t)(3 * CC) * CC;       // [1024,1024]
  short* qkvb = wpt + (size_t)CC * CC;            // [4096,3072]
  short* yb = qkvb + (size_t)M * 3 * CC;          // [4096,1024]
  short* vTb = yb + (size_t)M * CC;               // [2*16*64, 2048]

  prep_fused<<<3072, 256, 0, stream>>>(x, xb, W_attn, wat, W_proj, wpt);

  // qkv = x @ W_attn + b_attn; q-third scaled by 0.125 (folded attn scale)
  gemm_bt_mfma<true><<<dim3((3 * CC) / 128, M / 128), 256, 0, stream>>>(
      xb, wat, b_attn, qkvb, M, 3 * CC, CC, CC);

  transpose_v<<<dim3(TT / 64, BATCH * NH), 256, 0, stream>>>(qkvb, vTb);

  attn_mfma6<<<dim3(16, BATCH * NH), 256, 0, stream>>>(
      qkvb, vTb, attn_mask, yb);

  gemm_bt_mfma<false><<<dim3(CC / 128, M / 128), 256, 0, stream>>>(
      yb, wpt, b_proj, out, M, CC, CC, 0);
}